// Round 1
// baseline (991.985 us; speedup 1.0000x reference)
//
#include <hip/hip_runtime.h>

// NonLocalBlock fp32 baseline for MI355X.
// B=4, CIN=256, C=128, H=W=64 -> N=4096.
// Pipeline: proj (QKV) -> flash attention -> z-gemm (+LN partials) -> stats -> LN+residual.

#define BB   4
#define CINC 256
#define CCH  128
#define NS   4096
#define LN_EPS 1e-5f

__device__ __forceinline__ float4 ld4(const float* p) { return *reinterpret_cast<const float4*>(p); }
__device__ __forceinline__ void   st4(float* p, float4 v) { *reinterpret_cast<float4*>(p) = v; }

#define FMA4(acc, s, v)                                                        \
    do {                                                                       \
        (acc).x += (s) * (v).x;                                                \
        (acc).y += (s) * (v).y;                                                \
        (acc).z += (s) * (v).z;                                                \
        (acc).w += (s) * (v).w;                                                \
    } while (0)

__device__ __forceinline__ float dot4(float4 a, float4 b) {
    return a.x * b.x + a.y * b.y + a.z * b.z + a.w * b.w;
}

// ---------------------------------------------------------------------------
// Kernel 1: fused projection GEMM.
// Stacked rows: [0,128)=theta(Wt)->Q, [128,256)=phi(Wp)->K, [256,384)=g(Wg)->V.
// Out layout: [B][N][C] (row-major over C) for all three.
// Block computes 64(rows r) x 64(cols n), K-loop over CIN in 4 steps of 64.
// ---------------------------------------------------------------------------
__global__ __launch_bounds__(256) void proj_kernel(
    const float* __restrict__ x,
    const float* __restrict__ Wt, const float* __restrict__ bt,
    const float* __restrict__ Wp, const float* __restrict__ bp,
    const float* __restrict__ Wg, const float* __restrict__ bg,
    float* __restrict__ Q, float* __restrict__ K, float* __restrict__ V)
{
    __shared__ float Ws[64 * 64];   // W tile, rows swizzled (XOR on f4 chunk)
    __shared__ float Xs[64 * 68];   // x tile [k][n], padded stride 68

    const int tid = threadIdx.x;
    const int b   = blockIdx.z;
    const int rt  = blockIdx.y;          // 0..5
    const int n0  = blockIdx.x * 64;
    const int mid = rt >> 1;             // which matrix
    const int sub = (rt & 1) * 64;       // row offset inside that matrix

    const float* Wsel = (mid == 0) ? Wt : (mid == 1) ? Wp : Wg;
    const float* bsel = (mid == 0) ? bt : (mid == 1) ? bp : bg;
    float*       Out  = (mid == 0) ? Q  : (mid == 1) ? K  : V;

    const int q  = tid & 15;   // row group (rows q+16a)
    const int tj = tid >> 4;   // col group (cols 4*tj+jj)

    float4 acc[4];
#pragma unroll
    for (int a = 0; a < 4; ++a) acc[a] = make_float4(0.f, 0.f, 0.f, 0.f);

    for (int kb = 0; kb < 4; ++kb) {
#pragma unroll
        for (int u = 0; u < 4; ++u) {   // load W tile 64x64
            int fi = tid + 256 * u;
            int row = fi >> 4;
            int kc  = fi & 15;
            float4 v = ld4(&Wsel[(size_t)(sub + row) * CINC + kb * 64 + kc * 4]);
            st4(&Ws[row * 64 + (kc ^ (row & 7)) * 4], v);
        }
#pragma unroll
        for (int u = 0; u < 4; ++u) {   // load x tile 64x64
            int fi = tid + 256 * u;
            int k  = fi >> 4;
            int nc = fi & 15;
            float4 v = ld4(&x[(size_t)(b * CINC + kb * 64 + k) * NS + n0 + nc * 4]);
            st4(&Xs[k * 68 + nc * 4], v);
        }
        __syncthreads();

#pragma unroll 4
        for (int g = 0; g < 16; ++g) {
            float4 wv[4], xv[4];
#pragma unroll
            for (int a = 0; a < 4; ++a) {
                int r = q + 16 * a;
                wv[a] = ld4(&Ws[r * 64 + ((g ^ (r & 7)) & 15) * 4]);
            }
#pragma unroll
            for (int k2 = 0; k2 < 4; ++k2)
                xv[k2] = ld4(&Xs[(g * 4 + k2) * 68 + tj * 4]);
#pragma unroll
            for (int a = 0; a < 4; ++a) {
                FMA4(acc[a], wv[a].x, xv[0]);
                FMA4(acc[a], wv[a].y, xv[1]);
                FMA4(acc[a], wv[a].z, xv[2]);
                FMA4(acc[a], wv[a].w, xv[3]);
            }
        }
        __syncthreads();
    }

#pragma unroll
    for (int a = 0; a < 4; ++a) {
        int c = sub + q + 16 * a;        // channel in [0,128)
        float bias = bsel[c];
        float* base = &Out[((size_t)b * NS + n0 + 4 * tj) * CCH + c];
        base[0 * CCH] = acc[a].x + bias;
        base[1 * CCH] = acc[a].y + bias;
        base[2 * CCH] = acc[a].z + bias;
        base[3 * CCH] = acc[a].w + bias;
    }
}

// ---------------------------------------------------------------------------
// Kernel 2: flash attention, fp32. Block = 64 query rows, loops 64-key tiles.
// LDS: Qs/Ks swizzled, Vs linear, Ss stride 65. Y accumulated in registers.
// ---------------------------------------------------------------------------
__global__ __launch_bounds__(256) void attn_kernel(
    const float* __restrict__ Q, const float* __restrict__ K,
    const float* __restrict__ V, float* __restrict__ Y)
{
    __shared__ float Qs[64 * 128];
    __shared__ float Ks[64 * 128];
    __shared__ float Vs[64 * 128];
    __shared__ float Ss[64 * 65];

    const int tid = threadIdx.x;
    const int b   = blockIdx.y;
    const int n0  = blockIdx.x * 64;

    const int q    = tid & 15;   // phase-1 row group
    const int tj   = tid >> 4;   // phase-1 col group
    const int irow = tid >> 2;   // phase-2/3/4 row (0..63)
    const int p    = tid & 3;    // phase-2/3/4 part

    // load Q tile once (swizzled)
#pragma unroll
    for (int u = 0; u < 8; ++u) {
        int fi = tid + 256 * u;
        int row = fi >> 5;
        int kc  = fi & 31;
        float4 v = ld4(&Q[((size_t)b * NS + n0 + row) * CCH + kc * 4]);
        st4(&Qs[row * 128 + (kc ^ (row & 7)) * 4], v);
    }

    float4 y4[8];
#pragma unroll
    for (int u = 0; u < 8; ++u) y4[u] = make_float4(0.f, 0.f, 0.f, 0.f);
    float m_run = -1e30f, l_run = 0.f;

    for (int kt = 0; kt < 64; ++kt) {
        const int m0 = kt * 64;
#pragma unroll
        for (int u = 0; u < 8; ++u) {
            int fi = tid + 256 * u;
            int row = fi >> 5;
            int kc  = fi & 31;
            float4 kv = ld4(&K[((size_t)b * NS + m0 + row) * CCH + kc * 4]);
            st4(&Ks[row * 128 + (kc ^ (row & 7)) * 4], kv);
            float4 vv = ld4(&V[((size_t)b * NS + m0 + row) * CCH + kc * 4]);
            st4(&Vs[row * 128 + kc * 4], vv);
        }
        __syncthreads();

        // ---- phase 1: S = Q K^T (64x64, K=128) ----
        float4 acc[4];
#pragma unroll
        for (int a = 0; a < 4; ++a) acc[a] = make_float4(0.f, 0.f, 0.f, 0.f);
#pragma unroll 4
        for (int g = 0; g < 32; ++g) {
            float4 qv[4], kv[4];
#pragma unroll
            for (int a = 0; a < 4; ++a) {
                int r = q + 16 * a;
                qv[a] = ld4(&Qs[r * 128 + (g ^ (r & 7)) * 4]);
            }
#pragma unroll
            for (int jj = 0; jj < 4; ++jj) {
                int cj = 4 * tj + jj;
                kv[jj] = ld4(&Ks[cj * 128 + (g ^ (cj & 7)) * 4]);
            }
#pragma unroll
            for (int a = 0; a < 4; ++a) {
                acc[a].x += dot4(qv[a], kv[0]);
                acc[a].y += dot4(qv[a], kv[1]);
                acc[a].z += dot4(qv[a], kv[2]);
                acc[a].w += dot4(qv[a], kv[3]);
            }
        }
#pragma unroll
        for (int a = 0; a < 4; ++a) {
            int r = q + 16 * a;
            Ss[r * 65 + 4 * tj + 0] = acc[a].x;
            Ss[r * 65 + 4 * tj + 1] = acc[a].y;
            Ss[r * 65 + 4 * tj + 2] = acc[a].z;
            Ss[r * 65 + 4 * tj + 3] = acc[a].w;
        }
        __syncthreads();

        // ---- phase 2/3: online softmax (4 lanes per row) ----
        float mx = -1e30f;
#pragma unroll
        for (int j2 = 0; j2 < 16; ++j2)
            mx = fmaxf(mx, Ss[irow * 65 + p * 16 + j2]);
        mx = fmaxf(mx, __shfl_xor(mx, 1));
        mx = fmaxf(mx, __shfl_xor(mx, 2));
        float m_new = fmaxf(m_run, mx);
        float alpha = __expf(m_run - m_new);
        float psum = 0.f;
#pragma unroll
        for (int j2 = 0; j2 < 16; ++j2) {
            int idx = irow * 65 + p * 16 + j2;
            float val = __expf(Ss[idx] - m_new);
            Ss[idx] = val;
            psum += val;
        }
        psum += __shfl_xor(psum, 1);
        psum += __shfl_xor(psum, 2);
        l_run = l_run * alpha + psum;
        m_run = m_new;
#pragma unroll
        for (int u = 0; u < 8; ++u) {
            y4[u].x *= alpha; y4[u].y *= alpha; y4[u].z *= alpha; y4[u].w *= alpha;
        }

        // ---- phase 4: Y += P V  (row irow, channels c = p*4 + 16u) ----
        // Ss row irow written by this wave's own 4 lanes; Vs behind the barrier.
#pragma unroll 4
        for (int j = 0; j < 64; ++j) {
            float pv = Ss[irow * 65 + j];
#pragma unroll
            for (int u = 0; u < 8; ++u) {
                float4 vv = ld4(&Vs[j * 128 + (p + 4 * u) * 4]);
                FMA4(y4[u], pv, vv);
            }
        }
        __syncthreads();
    }

    const float inv_l = 1.0f / l_run;
#pragma unroll
    for (int u = 0; u < 8; ++u) {
        float4 o;
        o.x = y4[u].x * inv_l; o.y = y4[u].y * inv_l;
        o.z = y4[u].z * inv_l; o.w = y4[u].w * inv_l;
        st4(&Y[((size_t)b * NS + n0 + irow) * CCH + (p + 4 * u) * 4], o);
    }
}

// ---------------------------------------------------------------------------
// Kernel 3: z[o][n] = sum_c Wz[o][c]*Y[b][n][c] + bz[o]  (TN dot-product GEMM)
// plus deterministic per-block LN partial sums (sum, sumsq).
// ---------------------------------------------------------------------------
__global__ __launch_bounds__(256) void zgemm_kernel(
    const float* __restrict__ Y, const float* __restrict__ Wz,
    const float* __restrict__ bz, float* __restrict__ Z,
    float* __restrict__ partials)
{
    __shared__ float Ws2[64 * 128];  // Wz rows (o), swizzled
    __shared__ float Ys2[64 * 128];  // Y rows (n), swizzled
    __shared__ float red[8];

    const int tid = threadIdx.x;
    const int b   = blockIdx.z;
    const int ot  = blockIdx.y;
    const int n0  = blockIdx.x * 64;
    const int o0  = ot * 64;

#pragma unroll
    for (int u = 0; u < 8; ++u) {
        int fi = tid + 256 * u;
        int row = fi >> 5;
        int kc  = fi & 31;
        st4(&Ws2[row * 128 + (kc ^ (row & 7)) * 4],
            ld4(&Wz[(size_t)(o0 + row) * CCH + kc * 4]));
        st4(&Ys2[row * 128 + (kc ^ (row & 7)) * 4],
            ld4(&Y[((size_t)b * NS + n0 + row) * CCH + kc * 4]));
    }
    __syncthreads();

    const int q  = tid & 15;  // n rows q+16a
    const int tj = tid >> 4;  // o cols 4tj+jj

    float4 acc[4];
#pragma unroll
    for (int a = 0; a < 4; ++a) acc[a] = make_float4(0.f, 0.f, 0.f, 0.f);
#pragma unroll 4
    for (int g = 0; g < 32; ++g) {
        float4 yv[4], wv[4];
#pragma unroll
        for (int a = 0; a < 4; ++a) {
            int r = q + 16 * a;
            yv[a] = ld4(&Ys2[r * 128 + (g ^ (r & 7)) * 4]);
        }
#pragma unroll
        for (int jj = 0; jj < 4; ++jj) {
            int cj = 4 * tj + jj;
            wv[jj] = ld4(&Ws2[cj * 128 + (g ^ (cj & 7)) * 4]);
        }
#pragma unroll
        for (int a = 0; a < 4; ++a) {
            acc[a].x += dot4(yv[a], wv[0]);
            acc[a].y += dot4(yv[a], wv[1]);
            acc[a].z += dot4(yv[a], wv[2]);
            acc[a].w += dot4(yv[a], wv[3]);
        }
    }

    float4 bz4 = ld4(&bz[o0 + 4 * tj]);
    float s = 0.f, s2 = 0.f;
#pragma unroll
    for (int a = 0; a < 4; ++a) {
        int n = n0 + q + 16 * a;
        float v0 = acc[a].x + bz4.x;
        float v1 = acc[a].y + bz4.y;
        float v2 = acc[a].z + bz4.z;
        float v3 = acc[a].w + bz4.w;
        Z[(size_t)(b * CINC + o0 + 4 * tj + 0) * NS + n] = v0;
        Z[(size_t)(b * CINC + o0 + 4 * tj + 1) * NS + n] = v1;
        Z[(size_t)(b * CINC + o0 + 4 * tj + 2) * NS + n] = v2;
        Z[(size_t)(b * CINC + o0 + 4 * tj + 3) * NS + n] = v3;
        s  += v0 + v1 + v2 + v3;
        s2 += v0 * v0 + v1 * v1 + v2 * v2 + v3 * v3;
    }
#pragma unroll
    for (int off = 1; off < 64; off <<= 1) {
        s  += __shfl_xor(s, off);
        s2 += __shfl_xor(s2, off);
    }
    if ((tid & 63) == 0) { red[(tid >> 6) * 2] = s; red[(tid >> 6) * 2 + 1] = s2; }
    __syncthreads();
    if (tid == 0) {
        float ts  = red[0] + red[2] + red[4] + red[6];
        float ts2 = red[1] + red[3] + red[5] + red[7];
        int pidx = b * 256 + ot * 64 + blockIdx.x;
        partials[pidx * 2 + 0] = ts;
        partials[pidx * 2 + 1] = ts2;
    }
}

// ---------------------------------------------------------------------------
// Kernel 4: reduce per-block partials -> per-batch (mean, rstd). Deterministic.
// ---------------------------------------------------------------------------
__global__ void ln_stats_kernel(const float* __restrict__ partials,
                                float* __restrict__ stats)
{
    const int b = blockIdx.x;
    const int t = threadIdx.x;  // 64 threads
    float s = 0.f, s2 = 0.f;
#pragma unroll
    for (int u = 0; u < 4; ++u) {
        const float* pp = &partials[(size_t)(b * 256 + t + 64 * u) * 2];
        s  += pp[0];
        s2 += pp[1];
    }
#pragma unroll
    for (int off = 1; off < 64; off <<= 1) {
        s  += __shfl_xor(s, off);
        s2 += __shfl_xor(s2, off);
    }
    if (t == 0) {
        const float M = 1048576.f;  // CIN*H*W
        float mean = s / M;
        float var  = s2 / M - mean * mean;
        stats[b * 2 + 0] = mean;
        stats[b * 2 + 1] = rsqrtf(var + LN_EPS);
    }
}

// ---------------------------------------------------------------------------
// Kernel 5: out = (z - mean)*rstd*gamma + beta + x
// ---------------------------------------------------------------------------
__global__ __launch_bounds__(256) void final_kernel(
    const float* __restrict__ Z, const float* __restrict__ x,
    const float* __restrict__ gamma, const float* __restrict__ beta,
    const float* __restrict__ stats, float* __restrict__ out)
{
    const int total4 = BB * CINC * NS / 4;  // 2^20
    for (int i4 = blockIdx.x * 256 + threadIdx.x; i4 < total4;
         i4 += gridDim.x * 256) {
        int b  = i4 >> 18;                  // CIN*NS/4 = 2^18
        int r4 = i4 & ((1 << 18) - 1);
        float mean = stats[b * 2 + 0];
        float rstd = stats[b * 2 + 1];
        float4 zv = ld4(&Z[(size_t)i4 * 4]);
        float4 xv = ld4(&x[(size_t)i4 * 4]);
        float4 gv = ld4(&gamma[(size_t)r4 * 4]);
        float4 bv = ld4(&beta[(size_t)r4 * 4]);
        float4 o;
        o.x = (zv.x - mean) * rstd * gv.x + bv.x + xv.x;
        o.y = (zv.y - mean) * rstd * gv.y + bv.y + xv.y;
        o.z = (zv.z - mean) * rstd * gv.z + bv.z + xv.z;
        o.w = (zv.w - mean) * rstd * gv.w + bv.w + xv.w;
        st4(&out[(size_t)i4 * 4], o);
    }
}

extern "C" void kernel_launch(void* const* d_in, const int* in_sizes, int n_in,
                              void* d_out, int out_size, void* d_ws, size_t ws_size,
                              hipStream_t stream)
{
    const float* x     = (const float*)d_in[0];
    const float* Wg    = (const float*)d_in[1];
    const float* bg    = (const float*)d_in[2];
    const float* Wt    = (const float*)d_in[3];
    const float* bt    = (const float*)d_in[4];
    const float* Wp    = (const float*)d_in[5];
    const float* bp    = (const float*)d_in[6];
    const float* Wz    = (const float*)d_in[7];
    const float* bz    = (const float*)d_in[8];
    const float* gamma = (const float*)d_in[9];
    const float* beta  = (const float*)d_in[10];
    float* out = (float*)d_out;

    // workspace layout (floats): Q,K,V,Y [B][N][C]; Z [B][CIN][N]; partials; stats
    float* ws = (float*)d_ws;
    const size_t SZ = (size_t)BB * NS * CCH;  // 2,097,152
    float* Q = ws;
    float* K = Q + SZ;
    float* V = K + SZ;
    float* Y = V + SZ;
    float* Z = Y + SZ;
    float* partials = Z + (size_t)BB * CINC * NS;
    float* stats    = partials + BB * 256 * 2;
    // total: 4*SZ + B*CIN*NS + 2048 + 8 floats ~= 48.1 MB

    proj_kernel<<<dim3(64, 6, BB), 256, 0, stream>>>(x, Wt, bt, Wp, bp, Wg, bg,
                                                     Q, K, V);
    attn_kernel<<<dim3(64, BB), 256, 0, stream>>>(Q, K, V, Y);
    zgemm_kernel<<<dim3(64, 4, BB), 256, 0, stream>>>(Y, Wz, bz, Z, partials);
    ln_stats_kernel<<<dim3(BB), 64, 0, stream>>>(partials, stats);
    final_kernel<<<dim3(2048), 256, 0, stream>>>(Z, x, gamma, beta, stats, out);
}

// Round 2
// 508.122 us; speedup vs baseline: 1.9523x; 1.9523x over previous
//
#include <hip/hip_runtime.h>
#include <hip/hip_bf16.h>

// NonLocalBlock for MI355X. B=4, CIN=256, C=128, H=W=64 -> N=4096.
// proj (fp32 compute -> bf16-split Q/K, bf16 V^T) -> MFMA flash attention
// -> z-gemm fp32 (+LN partials) -> stats -> LN+residual.

#define BB   4
#define CINC 256
#define CCH  128
#define NS   4096
#define LN_EPS 1e-5f

typedef unsigned short ushort_t;
typedef unsigned int   uint_t;
typedef __bf16 bf16x8 __attribute__((ext_vector_type(8)));
typedef float  f32x4  __attribute__((ext_vector_type(4)));

__device__ __forceinline__ float4 ld4(const float* p) { return *reinterpret_cast<const float4*>(p); }
__device__ __forceinline__ void   st4(float* p, float4 v) { *reinterpret_cast<float4*>(p) = v; }

__device__ __forceinline__ ushort_t f2bf(float f) {
    __hip_bfloat16 h = __float2bfloat16(f);
    return *reinterpret_cast<ushort_t*>(&h);
}
__device__ __forceinline__ float bf2f(ushort_t u) {
    __hip_bfloat16 h = *reinterpret_cast<__hip_bfloat16*>(&u);
    return __bfloat162float(h);
}

#define FMA4(acc, s, v)                                                        \
    do {                                                                       \
        (acc).x += (s) * (v).x;                                                \
        (acc).y += (s) * (v).y;                                                \
        (acc).z += (s) * (v).z;                                                \
        (acc).w += (s) * (v).w;                                                \
    } while (0)

__device__ __forceinline__ float dot4(float4 a, float4 b) {
    return a.x * b.x + a.y * b.y + a.z * b.z + a.w * b.w;
}

// ---------------------------------------------------------------------------
// Kernel 1: fused projection GEMM (fp32 compute).
// mid 0: theta->Qhi/Qlo, mid 1: phi->Khi/Klo (both [B][N][C] bf16 split),
// mid 2: g->Vt ([B][C][N] bf16).
// ---------------------------------------------------------------------------
__global__ __launch_bounds__(256) void proj_kernel(
    const float* __restrict__ x,
    const float* __restrict__ Wt, const float* __restrict__ bt,
    const float* __restrict__ Wp, const float* __restrict__ bp,
    const float* __restrict__ Wg, const float* __restrict__ bg,
    ushort_t* __restrict__ Qhi, ushort_t* __restrict__ Qlo,
    ushort_t* __restrict__ Khi, ushort_t* __restrict__ Klo,
    ushort_t* __restrict__ Vt)
{
    __shared__ float Ws[64 * 64];
    __shared__ float Xs[64 * 68];

    const int tid = threadIdx.x;
    const int b   = blockIdx.z;
    const int rt  = blockIdx.y;          // 0..5
    const int n0  = blockIdx.x * 64;
    const int mid = rt >> 1;
    const int sub = (rt & 1) * 64;

    const float* Wsel = (mid == 0) ? Wt : (mid == 1) ? Wp : Wg;
    const float* bsel = (mid == 0) ? bt : (mid == 1) ? bp : bg;

    const int q  = tid & 15;
    const int tj = tid >> 4;

    float4 acc[4];
#pragma unroll
    for (int a = 0; a < 4; ++a) acc[a] = make_float4(0.f, 0.f, 0.f, 0.f);

    for (int kb = 0; kb < 4; ++kb) {
#pragma unroll
        for (int u = 0; u < 4; ++u) {
            int fi = tid + 256 * u;
            int row = fi >> 4;
            int kc  = fi & 15;
            float4 v = ld4(&Wsel[(size_t)(sub + row) * CINC + kb * 64 + kc * 4]);
            st4(&Ws[row * 64 + (kc ^ (row & 7)) * 4], v);
        }
#pragma unroll
        for (int u = 0; u < 4; ++u) {
            int fi = tid + 256 * u;
            int k  = fi >> 4;
            int nc = fi & 15;
            float4 v = ld4(&x[(size_t)(b * CINC + kb * 64 + k) * NS + n0 + nc * 4]);
            st4(&Xs[k * 68 + nc * 4], v);
        }
        __syncthreads();

#pragma unroll 4
        for (int g = 0; g < 16; ++g) {
            float4 wv[4], xv[4];
#pragma unroll
            for (int a = 0; a < 4; ++a) {
                int r = q + 16 * a;
                wv[a] = ld4(&Ws[r * 64 + ((g ^ (r & 7)) & 15) * 4]);
            }
#pragma unroll
            for (int k2 = 0; k2 < 4; ++k2)
                xv[k2] = ld4(&Xs[(g * 4 + k2) * 68 + tj * 4]);
#pragma unroll
            for (int a = 0; a < 4; ++a) {
                FMA4(acc[a], wv[a].x, xv[0]);
                FMA4(acc[a], wv[a].y, xv[1]);
                FMA4(acc[a], wv[a].z, xv[2]);
                FMA4(acc[a], wv[a].w, xv[3]);
            }
        }
        __syncthreads();
    }

    if (mid == 2) {
        // V^T: thread holds channel c = sub+q+16a, 4 consecutive n -> 8B store
#pragma unroll
        for (int a = 0; a < 4; ++a) {
            int c = sub + q + 16 * a;
            float bias = bsel[c];
            ushort4 v4;
            v4.x = f2bf(acc[a].x + bias);
            v4.y = f2bf(acc[a].y + bias);
            v4.z = f2bf(acc[a].z + bias);
            v4.w = f2bf(acc[a].w + bias);
            *reinterpret_cast<ushort4*>(&Vt[(size_t)(b * CCH + c) * NS + n0 + 4 * tj]) = v4;
        }
    } else {
        ushort_t* H = (mid == 0) ? Qhi : Khi;
        ushort_t* L = (mid == 0) ? Qlo : Klo;
        float vals[4][4];
#pragma unroll
        for (int a = 0; a < 4; ++a) {
            int c = sub + q + 16 * a;
            float bias = bsel[c];
            vals[a][0] = acc[a].x + bias;
            vals[a][1] = acc[a].y + bias;
            vals[a][2] = acc[a].z + bias;
            vals[a][3] = acc[a].w + bias;
        }
#pragma unroll
        for (int a = 0; a < 4; ++a) {
            int c = sub + q + 16 * a;
#pragma unroll
            for (int j = 0; j < 4; ++j) {
                float v = vals[a][j];
                ushort_t hb = f2bf(v);
                ushort_t lb = f2bf(v - bf2f(hb));
                size_t idx = (size_t)(b * NS + n0 + 4 * tj + j) * CCH + c;
                H[idx] = hb;
                L[idx] = lb;
            }
        }
    }
}

// ---------------------------------------------------------------------------
// Kernel 2: MFMA flash attention.
// Block = 64 q rows (4 waves x 16 q), loops 64-key tiles.
// S^T = mfma(K, Q) 3-pass split-bf16; softmax lane-local; PV via LDS P.
// ---------------------------------------------------------------------------
__global__ __launch_bounds__(256) void attn_kernel(
    const ushort_t* __restrict__ Qhi, const ushort_t* __restrict__ Qlo,
    const ushort_t* __restrict__ Khi, const ushort_t* __restrict__ Klo,
    const ushort_t* __restrict__ Vt, float* __restrict__ Y)
{
    __shared__ __align__(16) ushort_t Kh_lds[64 * 128];
    __shared__ __align__(16) ushort_t Kl_lds[64 * 128];
    __shared__ __align__(16) ushort_t Vt_lds[128 * 64];
    __shared__ __align__(16) ushort_t P_lds[4 * 16 * 64];

    const int tid  = threadIdx.x;
    const int w    = tid >> 6;
    const int lane = tid & 63;
    const int lq   = lane & 15;   // q within wave (QK domain), c within frag (PV)
    const int g    = lane >> 4;   // lane group 0..3
    const int b    = blockIdx.y;
    const int n0   = blockIdx.x * 64;

    // Q fragments in registers: B-frag (j=q=lq, k-dim c = cs*32 + 8g + b)
    bf16x8 qh[4], ql[4];
    {
        const ushort_t* qbh = Qhi + (size_t)(b * NS + n0 + w * 16 + lq) * CCH;
        const ushort_t* qbl = Qlo + (size_t)(b * NS + n0 + w * 16 + lq) * CCH;
#pragma unroll
        for (int cs = 0; cs < 4; ++cs) {
            qh[cs] = *reinterpret_cast<const bf16x8*>(qbh + cs * 32 + g * 8);
            ql[cs] = *reinterpret_cast<const bf16x8*>(qbl + cs * 32 + g * 8);
        }
    }

    f32x4 yacc[8];
#pragma unroll
    for (int cf = 0; cf < 8; ++cf) yacc[cf] = (f32x4){0.f, 0.f, 0.f, 0.f};
    float m_run = -1e30f, l_run = 0.f;

    const ushort_t* Khg = Khi + (size_t)b * NS * CCH;
    const ushort_t* Klg = Klo + (size_t)b * NS * CCH;
    const ushort_t* Vtg = Vt + (size_t)b * CCH * NS;

    for (int kt = 0; kt < 64; ++kt) {
        const int m0 = kt * 64;

        // ---- stage: global loads (before barrier), then swizzled ds_writes
        uint4 tK[4], tL[4], tV[4];
#pragma unroll
        for (int it = 0; it < 4; ++it) {
            int fi = it * 256 + tid;
            int kr = fi >> 4;
            int cc = fi & 15;
            tK[it] = *reinterpret_cast<const uint4*>(Khg + (size_t)(m0 + kr) * CCH + cc * 8);
            tL[it] = *reinterpret_cast<const uint4*>(Klg + (size_t)(m0 + kr) * CCH + cc * 8);
        }
#pragma unroll
        for (int it = 0; it < 4; ++it) {
            int fi = it * 256 + tid;
            int cr = fi >> 3;
            int kc = fi & 7;
            tV[it] = *reinterpret_cast<const uint4*>(Vtg + (size_t)cr * NS + m0 + kc * 8);
        }
        __syncthreads();   // everyone done reading previous tile
#pragma unroll
        for (int it = 0; it < 4; ++it) {
            int fi = it * 256 + tid;
            int kr = fi >> 4;
            int cc = fi & 15;
            int swz = (cc & 8) | ((cc & 7) ^ (kr & 7));
            *reinterpret_cast<uint4*>(&Kh_lds[kr * 128 + swz * 8]) = tK[it];
            *reinterpret_cast<uint4*>(&Kl_lds[kr * 128 + swz * 8]) = tL[it];
            int cr = fi >> 3;
            int kc = fi & 7;
            int swzv = kc ^ (cr & 7);
            *reinterpret_cast<uint4*>(&Vt_lds[cr * 64 + swzv * 8]) = tV[it];
        }
        __syncthreads();   // tile visible

        // ---- QK^T: T[k=16kk+4g+r][q=lq] via 3-pass split
        f32x4 tacc[4];
#pragma unroll
        for (int kk = 0; kk < 4; ++kk) tacc[kk] = (f32x4){0.f, 0.f, 0.f, 0.f};
#pragma unroll
        for (int cs = 0; cs < 4; ++cs) {
#pragma unroll
            for (int kk = 0; kk < 4; ++kk) {
                int kr = kk * 16 + lq;
                int cc = g + 4 * cs;
                int swz = (cc & 8) | ((cc & 7) ^ (kr & 7));
                bf16x8 ah = *reinterpret_cast<const bf16x8*>(&Kh_lds[kr * 128 + swz * 8]);
                bf16x8 al = *reinterpret_cast<const bf16x8*>(&Kl_lds[kr * 128 + swz * 8]);
                tacc[kk] = __builtin_amdgcn_mfma_f32_16x16x32_bf16(ah, qh[cs], tacc[kk], 0, 0, 0);
                tacc[kk] = __builtin_amdgcn_mfma_f32_16x16x32_bf16(al, qh[cs], tacc[kk], 0, 0, 0);
                tacc[kk] = __builtin_amdgcn_mfma_f32_16x16x32_bf16(ah, ql[cs], tacc[kk], 0, 0, 0);
            }
        }

        // ---- online softmax (lane holds 16 keys of row q=lq)
        float mx = -1e30f;
#pragma unroll
        for (int kk = 0; kk < 4; ++kk)
#pragma unroll
            for (int r = 0; r < 4; ++r) mx = fmaxf(mx, tacc[kk][r]);
        mx = fmaxf(mx, __shfl_xor(mx, 16));
        mx = fmaxf(mx, __shfl_xor(mx, 32));
        float m_new = fmaxf(m_run, mx);
        float alpha = __expf(m_run - m_new);
        float pr[4][4];
        float psum = 0.f;
#pragma unroll
        for (int kk = 0; kk < 4; ++kk)
#pragma unroll
            for (int r = 0; r < 4; ++r) {
                float v = __expf(tacc[kk][r] - m_new);
                pr[kk][r] = v;
                psum += v;
            }
        psum += __shfl_xor(psum, 16);
        psum += __shfl_xor(psum, 32);
        l_run = l_run * alpha + psum;
        m_run = m_new;

        // ---- pack P to bf16, wave-local swizzled LDS write
#pragma unroll
        for (int kk = 0; kk < 4; ++kk) {
            uint_t lo = (uint_t)f2bf(pr[kk][0]) | ((uint_t)f2bf(pr[kk][1]) << 16);
            uint_t hi = (uint_t)f2bf(pr[kk][2]) | ((uint_t)f2bf(pr[kk][3]) << 16);
            int kbase = kk * 16 + 4 * g;
            int swz = (kbase >> 3) ^ (lq & 7);
            uint2 val = make_uint2(lo, hi);
            *reinterpret_cast<uint2*>(&P_lds[w * 1024 + lq * 64 + swz * 8 + (kbase & 7)]) = val;
        }
        bf16x8 pa[2];
#pragma unroll
        for (int s = 0; s < 2; ++s) {
            int swz = (g + 4 * s) ^ (lq & 7);
            pa[s] = *reinterpret_cast<const bf16x8*>(&P_lds[w * 1024 + lq * 64 + swz * 8]);
        }

        // ---- rescale Y by alpha(q=4g+r), then Y += P V
        float a0 = __shfl(alpha, 4 * g + 0);
        float a1 = __shfl(alpha, 4 * g + 1);
        float a2 = __shfl(alpha, 4 * g + 2);
        float a3 = __shfl(alpha, 4 * g + 3);
#pragma unroll
        for (int cf = 0; cf < 8; ++cf) {
            yacc[cf][0] *= a0;
            yacc[cf][1] *= a1;
            yacc[cf][2] *= a2;
            yacc[cf][3] *= a3;
        }
#pragma unroll
        for (int cf = 0; cf < 8; ++cf) {
            int c = cf * 16 + lq;
#pragma unroll
            for (int s = 0; s < 2; ++s) {
                int swz = (g + 4 * s) ^ (c & 7);
                bf16x8 vb = *reinterpret_cast<const bf16x8*>(&Vt_lds[c * 64 + swz * 8]);
                yacc[cf] = __builtin_amdgcn_mfma_f32_16x16x32_bf16(pa[s], vb, yacc[cf], 0, 0, 0);
            }
        }
    }

    // ---- epilogue: normalize by l(q) and store Y fp32 [B][N][C]
    float invl = 1.0f / l_run;
    float r0 = __shfl(invl, 4 * g + 0);
    float r1 = __shfl(invl, 4 * g + 1);
    float r2 = __shfl(invl, 4 * g + 2);
    float r3 = __shfl(invl, 4 * g + 3);
    float rl[4] = {r0, r1, r2, r3};
#pragma unroll
    for (int cf = 0; cf < 8; ++cf) {
#pragma unroll
        for (int r = 0; r < 4; ++r) {
            size_t idx = (size_t)(b * NS + n0 + w * 16 + 4 * g + r) * CCH + cf * 16 + lq;
            Y[idx] = yacc[cf][r] * rl[r];
        }
    }
}

// ---------------------------------------------------------------------------
// Kernel 3: z = Wz . Y + bz (fp32), plus deterministic LN partials.
// ---------------------------------------------------------------------------
__global__ __launch_bounds__(256) void zgemm_kernel(
    const float* __restrict__ Y, const float* __restrict__ Wz,
    const float* __restrict__ bz, float* __restrict__ Z,
    float* __restrict__ partials)
{
    __shared__ float Ws2[64 * 128];
    __shared__ float Ys2[64 * 128];
    __shared__ float red[8];

    const int tid = threadIdx.x;
    const int b   = blockIdx.z;
    const int ot  = blockIdx.y;
    const int n0  = blockIdx.x * 64;
    const int o0  = ot * 64;

#pragma unroll
    for (int u = 0; u < 8; ++u) {
        int fi = tid + 256 * u;
        int row = fi >> 5;
        int kc  = fi & 31;
        st4(&Ws2[row * 128 + (kc ^ (row & 7)) * 4],
            ld4(&Wz[(size_t)(o0 + row) * CCH + kc * 4]));
        st4(&Ys2[row * 128 + (kc ^ (row & 7)) * 4],
            ld4(&Y[((size_t)b * NS + n0 + row) * CCH + kc * 4]));
    }
    __syncthreads();

    const int q  = tid & 15;
    const int tj = tid >> 4;

    float4 acc[4];
#pragma unroll
    for (int a = 0; a < 4; ++a) acc[a] = make_float4(0.f, 0.f, 0.f, 0.f);
#pragma unroll 4
    for (int g = 0; g < 32; ++g) {
        float4 yv[4], wv[4];
#pragma unroll
        for (int a = 0; a < 4; ++a) {
            int r = q + 16 * a;
            yv[a] = ld4(&Ys2[r * 128 + (g ^ (r & 7)) * 4]);
        }
#pragma unroll
        for (int jj = 0; jj < 4; ++jj) {
            int cj = 4 * tj + jj;
            wv[jj] = ld4(&Ws2[cj * 128 + (g ^ (cj & 7)) * 4]);
        }
#pragma unroll
        for (int a = 0; a < 4; ++a) {
            acc[a].x += dot4(yv[a], wv[0]);
            acc[a].y += dot4(yv[a], wv[1]);
            acc[a].z += dot4(yv[a], wv[2]);
            acc[a].w += dot4(yv[a], wv[3]);
        }
    }

    float4 bz4 = ld4(&bz[o0 + 4 * tj]);
    float s = 0.f, s2 = 0.f;
#pragma unroll
    for (int a = 0; a < 4; ++a) {
        int n = n0 + q + 16 * a;
        float v0 = acc[a].x + bz4.x;
        float v1 = acc[a].y + bz4.y;
        float v2 = acc[a].z + bz4.z;
        float v3 = acc[a].w + bz4.w;
        Z[(size_t)(b * CINC + o0 + 4 * tj + 0) * NS + n] = v0;
        Z[(size_t)(b * CINC + o0 + 4 * tj + 1) * NS + n] = v1;
        Z[(size_t)(b * CINC + o0 + 4 * tj + 2) * NS + n] = v2;
        Z[(size_t)(b * CINC + o0 + 4 * tj + 3) * NS + n] = v3;
        s  += v0 + v1 + v2 + v3;
        s2 += v0 * v0 + v1 * v1 + v2 * v2 + v3 * v3;
    }
#pragma unroll
    for (int off = 1; off < 64; off <<= 1) {
        s  += __shfl_xor(s, off);
        s2 += __shfl_xor(s2, off);
    }
    if ((tid & 63) == 0) { red[(tid >> 6) * 2] = s; red[(tid >> 6) * 2 + 1] = s2; }
    __syncthreads();
    if (tid == 0) {
        float ts  = red[0] + red[2] + red[4] + red[6];
        float ts2 = red[1] + red[3] + red[5] + red[7];
        int pidx = b * 256 + ot * 64 + blockIdx.x;
        partials[pidx * 2 + 0] = ts;
        partials[pidx * 2 + 1] = ts2;
    }
}

// ---------------------------------------------------------------------------
// Kernel 4: reduce partials -> per-batch (mean, rstd).
// ---------------------------------------------------------------------------
__global__ void ln_stats_kernel(const float* __restrict__ partials,
                                float* __restrict__ stats)
{
    const int b = blockIdx.x;
    const int t = threadIdx.x;  // 64
    float s = 0.f, s2 = 0.f;
#pragma unroll
    for (int u = 0; u < 4; ++u) {
        const float* pp = &partials[(size_t)(b * 256 + t + 64 * u) * 2];
        s  += pp[0];
        s2 += pp[1];
    }
#pragma unroll
    for (int off = 1; off < 64; off <<= 1) {
        s  += __shfl_xor(s, off);
        s2 += __shfl_xor(s2, off);
    }
    if (t == 0) {
        const float M = 1048576.f;
        float mean = s / M;
        float var  = s2 / M - mean * mean;
        stats[b * 2 + 0] = mean;
        stats[b * 2 + 1] = rsqrtf(var + LN_EPS);
    }
}

// ---------------------------------------------------------------------------
// Kernel 5: out = (z - mean)*rstd*gamma + beta + x
// ---------------------------------------------------------------------------
__global__ __launch_bounds__(256) void final_kernel(
    const float* __restrict__ Z, const float* __restrict__ x,
    const float* __restrict__ gamma, const float* __restrict__ beta,
    const float* __restrict__ stats, float* __restrict__ out)
{
    const int total4 = BB * CINC * NS / 4;
    for (int i4 = blockIdx.x * 256 + threadIdx.x; i4 < total4;
         i4 += gridDim.x * 256) {
        int b  = i4 >> 18;
        int r4 = i4 & ((1 << 18) - 1);
        float mean = stats[b * 2 + 0];
        float rstd = stats[b * 2 + 1];
        float4 zv = ld4(&Z[(size_t)i4 * 4]);
        float4 xv = ld4(&x[(size_t)i4 * 4]);
        float4 gv = ld4(&gamma[(size_t)r4 * 4]);
        float4 bv = ld4(&beta[(size_t)r4 * 4]);
        float4 o;
        o.x = (zv.x - mean) * rstd * gv.x + bv.x + xv.x;
        o.y = (zv.y - mean) * rstd * gv.y + bv.y + xv.y;
        o.z = (zv.z - mean) * rstd * gv.z + bv.z + xv.z;
        o.w = (zv.w - mean) * rstd * gv.w + bv.w + xv.w;
        st4(&out[(size_t)i4 * 4], o);
    }
}

extern "C" void kernel_launch(void* const* d_in, const int* in_sizes, int n_in,
                              void* d_out, int out_size, void* d_ws, size_t ws_size,
                              hipStream_t stream)
{
    const float* x     = (const float*)d_in[0];
    const float* Wg    = (const float*)d_in[1];
    const float* bg    = (const float*)d_in[2];
    const float* Wt    = (const float*)d_in[3];
    const float* bt    = (const float*)d_in[4];
    const float* Wp    = (const float*)d_in[5];
    const float* bp    = (const float*)d_in[6];
    const float* Wz    = (const float*)d_in[7];
    const float* bz    = (const float*)d_in[8];
    const float* gamma = (const float*)d_in[9];
    const float* beta  = (const float*)d_in[10];
    float* out = (float*)d_out;

    // workspace: Qhi,Qlo,Khi,Klo [B][N][C] bf16 (4MB each); Vt [B][C][N] bf16
    // (4MB); Y fp32 (8MB); Z fp32 (16MB); partials+stats.  ~44 MB total.
    char* p = (char*)d_ws;
    const size_t SZH = (size_t)BB * NS * CCH * sizeof(ushort_t);  // 4 MB
    ushort_t* Qhi = (ushort_t*)p; p += SZH;
    ushort_t* Qlo = (ushort_t*)p; p += SZH;
    ushort_t* Khi = (ushort_t*)p; p += SZH;
    ushort_t* Klo = (ushort_t*)p; p += SZH;
    ushort_t* Vt  = (ushort_t*)p; p += SZH;
    float* Y = (float*)p; p += (size_t)BB * NS * CCH * sizeof(float);
    float* Z = (float*)p; p += (size_t)BB * CINC * NS * sizeof(float);
    float* partials = (float*)p; p += BB * 256 * 2 * sizeof(float);
    float* stats    = (float*)p;

    proj_kernel<<<dim3(64, 6, BB), 256, 0, stream>>>(x, Wt, bt, Wp, bp, Wg, bg,
                                                     Qhi, Qlo, Khi, Klo, Vt);
    attn_kernel<<<dim3(64, BB), 256, 0, stream>>>(Qhi, Qlo, Khi, Klo, Vt, Y);
    zgemm_kernel<<<dim3(64, 4, BB), 256, 0, stream>>>(Y, Wz, bz, Z, partials);
    ln_stats_kernel<<<dim3(BB), 64, 0, stream>>>(partials, stats);
    final_kernel<<<dim3(2048), 256, 0, stream>>>(Z, x, gamma, beta, stats, out);
}

// Round 3
// 354.399 us; speedup vs baseline: 2.7991x; 1.4338x over previous
//
#include <hip/hip_runtime.h>
#include <hip/hip_bf16.h>

// NonLocalBlock for MI355X. B=4, CIN=256, C=128, H=W=64 -> N=4096.
// proj (fp32 -> bf16-split Q/K, bf16 V^T) -> MFMA flash attention (KV-split 2,
// 2-phase pipelined) -> z-gemm fp32 (+merge of attention halves, +LN partials)
// -> stats -> LN+residual.

#define BB   4
#define CINC 256
#define CCH  128
#define NS   4096
#define LN_EPS 1e-5f

typedef unsigned short ushort_t;
typedef unsigned int   uint_t;
typedef __bf16 bf16x8 __attribute__((ext_vector_type(8)));
typedef float  f32x4  __attribute__((ext_vector_type(4)));

__device__ __forceinline__ float4 ld4(const float* p) { return *reinterpret_cast<const float4*>(p); }
__device__ __forceinline__ void   st4(float* p, float4 v) { *reinterpret_cast<float4*>(p) = v; }

__device__ __forceinline__ ushort_t f2bf(float f) {
    __hip_bfloat16 h = __float2bfloat16(f);
    return *reinterpret_cast<ushort_t*>(&h);
}
__device__ __forceinline__ float bf2f(ushort_t u) {
    __hip_bfloat16 h = *reinterpret_cast<__hip_bfloat16*>(&u);
    return __bfloat162float(h);
}

#define FMA4(acc, s, v)                                                        \
    do {                                                                       \
        (acc).x += (s) * (v).x;                                                \
        (acc).y += (s) * (v).y;                                                \
        (acc).z += (s) * (v).z;                                                \
        (acc).w += (s) * (v).w;                                                \
    } while (0)

__device__ __forceinline__ float dot4(float4 a, float4 b) {
    return a.x * b.x + a.y * b.y + a.z * b.z + a.w * b.w;
}

// ---------------------------------------------------------------------------
// Kernel 1: fused projection GEMM (fp32 compute).
// mid 0: theta->Qhi/Qlo, mid 1: phi->Khi/Klo ([B][N][C] bf16 split, coalesced
// via LDS transpose), mid 2: g->Vt ([B][C][N] bf16).
// ---------------------------------------------------------------------------
__global__ __launch_bounds__(256) void proj_kernel(
    const float* __restrict__ x,
    const float* __restrict__ Wt, const float* __restrict__ bt,
    const float* __restrict__ Wp, const float* __restrict__ bp,
    const float* __restrict__ Wg, const float* __restrict__ bg,
    ushort_t* __restrict__ Qhi, ushort_t* __restrict__ Qlo,
    ushort_t* __restrict__ Khi, ushort_t* __restrict__ Klo,
    ushort_t* __restrict__ Vt)
{
    __shared__ float Ws[64 * 64];
    __shared__ float Xs[64 * 68];   // reused as transpose buffer T[64][68]

    const int tid = threadIdx.x;
    const int b   = blockIdx.z;
    const int rt  = blockIdx.y;          // 0..5
    const int n0  = blockIdx.x * 64;
    const int mid = rt >> 1;
    const int sub = (rt & 1) * 64;

    const float* Wsel = (mid == 0) ? Wt : (mid == 1) ? Wp : Wg;
    const float* bsel = (mid == 0) ? bt : (mid == 1) ? bp : bg;

    const int q  = tid & 15;
    const int tj = tid >> 4;

    float4 acc[4];
#pragma unroll
    for (int a = 0; a < 4; ++a) acc[a] = make_float4(0.f, 0.f, 0.f, 0.f);

    for (int kb = 0; kb < 4; ++kb) {
#pragma unroll
        for (int u = 0; u < 4; ++u) {
            int fi = tid + 256 * u;
            int row = fi >> 4;
            int kc  = fi & 15;
            float4 v = ld4(&Wsel[(size_t)(sub + row) * CINC + kb * 64 + kc * 4]);
            st4(&Ws[row * 64 + (kc ^ (row & 7)) * 4], v);
        }
#pragma unroll
        for (int u = 0; u < 4; ++u) {
            int fi = tid + 256 * u;
            int k  = fi >> 4;
            int nc = fi & 15;
            float4 v = ld4(&x[(size_t)(b * CINC + kb * 64 + k) * NS + n0 + nc * 4]);
            st4(&Xs[k * 68 + nc * 4], v);
        }
        __syncthreads();

#pragma unroll 4
        for (int g = 0; g < 16; ++g) {
            float4 wv[4], xv[4];
#pragma unroll
            for (int a = 0; a < 4; ++a) {
                int r = q + 16 * a;
                wv[a] = ld4(&Ws[r * 64 + ((g ^ (r & 7)) & 15) * 4]);
            }
#pragma unroll
            for (int k2 = 0; k2 < 4; ++k2)
                xv[k2] = ld4(&Xs[(g * 4 + k2) * 68 + tj * 4]);
#pragma unroll
            for (int a = 0; a < 4; ++a) {
                FMA4(acc[a], wv[a].x, xv[0]);
                FMA4(acc[a], wv[a].y, xv[1]);
                FMA4(acc[a], wv[a].z, xv[2]);
                FMA4(acc[a], wv[a].w, xv[3]);
            }
        }
        __syncthreads();
    }

    if (mid == 2) {
        // V^T: thread holds channel c = sub+q+16a, 4 consecutive n -> 8B store
#pragma unroll
        for (int a = 0; a < 4; ++a) {
            int c = sub + q + 16 * a;
            float bias = bsel[c];
            ushort4 v4;
            v4.x = f2bf(acc[a].x + bias);
            v4.y = f2bf(acc[a].y + bias);
            v4.z = f2bf(acc[a].z + bias);
            v4.w = f2bf(acc[a].w + bias);
            *reinterpret_cast<ushort4*>(&Vt[(size_t)(b * CCH + c) * NS + n0 + 4 * tj]) = v4;
        }
    } else {
        ushort_t* H = (mid == 0) ? Qhi : Khi;
        ushort_t* L = (mid == 0) ? Qlo : Klo;
        float* T = Xs;   // [64 n][stride 68] transpose buffer (16B-aligned rows)
#pragma unroll
        for (int a = 0; a < 4; ++a) {
            float bias = bsel[sub + q + 16 * a];
            T[(4 * tj + 0) * 68 + q + 16 * a] = acc[a].x + bias;
            T[(4 * tj + 1) * 68 + q + 16 * a] = acc[a].y + bias;
            T[(4 * tj + 2) * 68 + q + 16 * a] = acc[a].z + bias;
            T[(4 * tj + 3) * 68 + q + 16 * a] = acc[a].w + bias;
        }
        __syncthreads();
#pragma unroll
        for (int u = 0; u < 2; ++u) {
            int task = u * 256 + tid;
            int n  = task >> 3;
            int c0 = (task & 7) * 8;
            float4 lo4 = ld4(&T[n * 68 + c0]);
            float4 hi4 = ld4(&T[n * 68 + c0 + 4]);
            float v[8] = {lo4.x, lo4.y, lo4.z, lo4.w, hi4.x, hi4.y, hi4.z, hi4.w};
            uint_t hw[4], lw[4];
#pragma unroll
            for (int j = 0; j < 4; ++j) {
                ushort_t h0 = f2bf(v[2 * j]);
                ushort_t h1 = f2bf(v[2 * j + 1]);
                ushort_t e0 = f2bf(v[2 * j] - bf2f(h0));
                ushort_t e1 = f2bf(v[2 * j + 1] - bf2f(h1));
                hw[j] = (uint_t)h0 | ((uint_t)h1 << 16);
                lw[j] = (uint_t)e0 | ((uint_t)e1 << 16);
            }
            size_t idx = (size_t)(b * NS + n0 + n) * CCH + sub + c0;
            *reinterpret_cast<uint4*>(&H[idx]) = make_uint4(hw[0], hw[1], hw[2], hw[3]);
            *reinterpret_cast<uint4*>(&L[idx]) = make_uint4(lw[0], lw[1], lw[2], lw[3]);
        }
    }
}

// ---------------------------------------------------------------------------
// Kernel 2: MFMA flash attention, KV-split 2, 2-phase pipelined.
// Block = 64 q rows x 2048 keys (half h). Writes unnormalized Y + (m,l).
// ---------------------------------------------------------------------------
__global__ __launch_bounds__(256) void attn_kernel(
    const ushort_t* __restrict__ Qhi, const ushort_t* __restrict__ Qlo,
    const ushort_t* __restrict__ Khi, const ushort_t* __restrict__ Klo,
    const ushort_t* __restrict__ Vt, float* __restrict__ Yp,
    float* __restrict__ ML)
{
    __shared__ __align__(16) ushort_t Kh_lds[64 * 128];
    __shared__ __align__(16) ushort_t Kl_lds[64 * 128];
    __shared__ __align__(16) ushort_t Vt_lds[128 * 64];
    __shared__ __align__(16) ushort_t P_lds[4 * 16 * 64];

    const int tid  = threadIdx.x;
    const int w    = tid >> 6;
    const int lane = tid & 63;
    const int lq   = lane & 15;
    const int g    = lane >> 4;
    const int n0   = blockIdx.x * 64;
    const int h    = blockIdx.y;    // KV half
    const int b    = blockIdx.z;

    // Q fragments in registers
    bf16x8 qh[4], ql[4];
    {
        const ushort_t* qbh = Qhi + (size_t)(b * NS + n0 + w * 16 + lq) * CCH;
        const ushort_t* qbl = Qlo + (size_t)(b * NS + n0 + w * 16 + lq) * CCH;
#pragma unroll
        for (int cs = 0; cs < 4; ++cs) {
            qh[cs] = *reinterpret_cast<const bf16x8*>(qbh + cs * 32 + g * 8);
            ql[cs] = *reinterpret_cast<const bf16x8*>(qbl + cs * 32 + g * 8);
        }
    }

    f32x4 yacc[8];
#pragma unroll
    for (int cf = 0; cf < 8; ++cf) yacc[cf] = (f32x4){0.f, 0.f, 0.f, 0.f};
    float m_run = -1e30f, l_run = 0.f;

    const ushort_t* Khg = Khi + (size_t)b * NS * CCH;
    const ushort_t* Klg = Klo + (size_t)b * NS * CCH;
    const ushort_t* Vtg = Vt + (size_t)b * CCH * NS;

    const int NT = 32;
    const int ktbase = h * 32;

    uint4 tK[4], tL[4], tV[4];

    auto load_tile = [&](int ktg) {
        const int m0 = ktg * 64;
#pragma unroll
        for (int it = 0; it < 4; ++it) {
            int fi = it * 256 + tid;
            int kr = fi >> 4;
            int cc = fi & 15;
            tK[it] = *reinterpret_cast<const uint4*>(Khg + (size_t)(m0 + kr) * CCH + cc * 8);
            tL[it] = *reinterpret_cast<const uint4*>(Klg + (size_t)(m0 + kr) * CCH + cc * 8);
        }
#pragma unroll
        for (int it = 0; it < 4; ++it) {
            int fi = it * 256 + tid;
            int cr = fi >> 3;
            int kc = fi & 7;
            tV[it] = *reinterpret_cast<const uint4*>(Vtg + (size_t)cr * NS + m0 + kc * 8);
        }
    };
    auto write_tile = [&]() {
#pragma unroll
        for (int it = 0; it < 4; ++it) {
            int fi = it * 256 + tid;
            int kr = fi >> 4;
            int cc = fi & 15;
            int swz = (cc & 8) | ((cc & 7) ^ (kr & 7));
            *reinterpret_cast<uint4*>(&Kh_lds[kr * 128 + swz * 8]) = tK[it];
            *reinterpret_cast<uint4*>(&Kl_lds[kr * 128 + swz * 8]) = tL[it];
            int cr = fi >> 3;
            int kc = fi & 7;
            int swzv = kc ^ (cr & 7);
            *reinterpret_cast<uint4*>(&Vt_lds[cr * 64 + swzv * 8]) = tV[it];
        }
    };

    // prologue: stage tile 0
    load_tile(ktbase);
    write_tile();
    __syncthreads();

    for (int kt = 0; kt < NT; ++kt) {
        const bool more = (kt + 1 < NT);
        if (more) load_tile(ktbase + kt + 1);   // prefetch into regs

        // ---- QK^T: T[k=16kk+4g+r][q=lq] via 3-pass split
        f32x4 tacc[4];
#pragma unroll
        for (int kk = 0; kk < 4; ++kk) tacc[kk] = (f32x4){0.f, 0.f, 0.f, 0.f};
#pragma unroll
        for (int cs = 0; cs < 4; ++cs) {
#pragma unroll
            for (int kk = 0; kk < 4; ++kk) {
                int kr = kk * 16 + lq;
                int cc = g + 4 * cs;
                int swz = (cc & 8) | ((cc & 7) ^ (kr & 7));
                bf16x8 ah = *reinterpret_cast<const bf16x8*>(&Kh_lds[kr * 128 + swz * 8]);
                bf16x8 al = *reinterpret_cast<const bf16x8*>(&Kl_lds[kr * 128 + swz * 8]);
                tacc[kk] = __builtin_amdgcn_mfma_f32_16x16x32_bf16(ah, qh[cs], tacc[kk], 0, 0, 0);
                tacc[kk] = __builtin_amdgcn_mfma_f32_16x16x32_bf16(al, qh[cs], tacc[kk], 0, 0, 0);
                tacc[kk] = __builtin_amdgcn_mfma_f32_16x16x32_bf16(ah, ql[cs], tacc[kk], 0, 0, 0);
            }
        }

        // ---- online softmax (lane holds 16 keys of row q=lq)
        float mx = -1e30f;
#pragma unroll
        for (int kk = 0; kk < 4; ++kk)
#pragma unroll
            for (int r = 0; r < 4; ++r) mx = fmaxf(mx, tacc[kk][r]);
        mx = fmaxf(mx, __shfl_xor(mx, 16));
        mx = fmaxf(mx, __shfl_xor(mx, 32));
        float m_new = fmaxf(m_run, mx);
        float alpha = __expf(m_run - m_new);
        float pr[4][4];
        float psum = 0.f;
#pragma unroll
        for (int kk = 0; kk < 4; ++kk)
#pragma unroll
            for (int r = 0; r < 4; ++r) {
                float v = __expf(tacc[kk][r] - m_new);
                pr[kk][r] = v;
                psum += v;
            }
        psum += __shfl_xor(psum, 16);
        psum += __shfl_xor(psum, 32);
        l_run = l_run * alpha + psum;
        m_run = m_new;

        // ---- pack P to bf16, wave-local swizzled LDS round trip
#pragma unroll
        for (int kk = 0; kk < 4; ++kk) {
            uint_t lo = (uint_t)f2bf(pr[kk][0]) | ((uint_t)f2bf(pr[kk][1]) << 16);
            uint_t hi = (uint_t)f2bf(pr[kk][2]) | ((uint_t)f2bf(pr[kk][3]) << 16);
            int kbase = kk * 16 + 4 * g;
            int swz = (kbase >> 3) ^ (lq & 7);
            uint2 val = make_uint2(lo, hi);
            *reinterpret_cast<uint2*>(&P_lds[w * 1024 + lq * 64 + swz * 8 + (kbase & 7)]) = val;
        }
        bf16x8 pa[2];
#pragma unroll
        for (int s = 0; s < 2; ++s) {
            int swz = (g + 4 * s) ^ (lq & 7);
            pa[s] = *reinterpret_cast<const bf16x8*>(&P_lds[w * 1024 + lq * 64 + swz * 8]);
        }

        // ---- rescale Y by alpha(q=4g+r), then Y += P V
        float a0 = __shfl(alpha, 4 * g + 0);
        float a1 = __shfl(alpha, 4 * g + 1);
        float a2 = __shfl(alpha, 4 * g + 2);
        float a3 = __shfl(alpha, 4 * g + 3);
#pragma unroll
        for (int cf = 0; cf < 8; ++cf) {
            yacc[cf][0] *= a0;
            yacc[cf][1] *= a1;
            yacc[cf][2] *= a2;
            yacc[cf][3] *= a3;
        }
#pragma unroll
        for (int cf = 0; cf < 8; ++cf) {
            int c = cf * 16 + lq;
#pragma unroll
            for (int s = 0; s < 2; ++s) {
                int swz = (g + 4 * s) ^ (c & 7);
                bf16x8 vb = *reinterpret_cast<const bf16x8*>(&Vt_lds[c * 64 + swz * 8]);
                yacc[cf] = __builtin_amdgcn_mfma_f32_16x16x32_bf16(pa[s], vb, yacc[cf], 0, 0, 0);
            }
        }

        if (more) {
            __syncthreads();   // all waves done reading LDS tile kt
            write_tile();      // (compiler inserts vmcnt wait for prefetch)
            __syncthreads();   // tile kt+1 visible
        }
    }

    // ---- epilogue: store unnormalized Y + (m,l)
#pragma unroll
    for (int cf = 0; cf < 8; ++cf) {
#pragma unroll
        for (int r = 0; r < 4; ++r) {
            size_t idx = ((size_t)(h * BB + b) * NS + n0 + w * 16 + 4 * g + r) * CCH + cf * 16 + lq;
            Yp[idx] = yacc[cf][r];
        }
    }
    if (g == 0) {
        size_t mi = ((size_t)(h * BB + b) * NS + n0 + w * 16 + lq) * 2;
        ML[mi + 0] = m_run;
        ML[mi + 1] = l_run;
    }
}

// ---------------------------------------------------------------------------
// Kernel 3: z = Wz . Y + bz (fp32) with on-the-fly merge of the two attention
// halves, plus deterministic LN partial sums.
// ---------------------------------------------------------------------------
__global__ __launch_bounds__(256) void zgemm_kernel(
    const float* __restrict__ Yp, const float* __restrict__ ML,
    const float* __restrict__ Wz, const float* __restrict__ bz,
    float* __restrict__ Z, float* __restrict__ partials)
{
    __shared__ float Ws2[64 * 128];
    __shared__ float Ys2[64 * 128];
    __shared__ float a01[64][2];
    __shared__ float red[8];

    const int tid = threadIdx.x;
    const int b   = blockIdx.z;
    const int ot  = blockIdx.y;
    const int n0  = blockIdx.x * 64;
    const int o0  = ot * 64;

    const float* Y0 = Yp + (size_t)(0 * BB + b) * NS * CCH;
    const float* Y1 = Yp + (size_t)(1 * BB + b) * NS * CCH;

    if (tid < 64) {
        int n = n0 + tid;
        float m0 = ML[((size_t)(0 * BB + b) * NS + n) * 2 + 0];
        float l0 = ML[((size_t)(0 * BB + b) * NS + n) * 2 + 1];
        float m1 = ML[((size_t)(1 * BB + b) * NS + n) * 2 + 0];
        float l1 = ML[((size_t)(1 * BB + b) * NS + n) * 2 + 1];
        float m  = fmaxf(m0, m1);
        float w0 = __expf(m0 - m), w1 = __expf(m1 - m);
        float inv = 1.0f / (l0 * w0 + l1 * w1);
        a01[tid][0] = w0 * inv;
        a01[tid][1] = w1 * inv;
    }
    __syncthreads();

#pragma unroll
    for (int u = 0; u < 8; ++u) {
        int fi = tid + 256 * u;
        int row = fi >> 5;
        int kc  = fi & 31;
        st4(&Ws2[row * 128 + (kc ^ (row & 7)) * 4],
            ld4(&Wz[(size_t)(o0 + row) * CCH + kc * 4]));
        float4 y0 = ld4(&Y0[(size_t)(n0 + row) * CCH + kc * 4]);
        float4 y1 = ld4(&Y1[(size_t)(n0 + row) * CCH + kc * 4]);
        float A0 = a01[row][0], A1 = a01[row][1];
        float4 ym;
        ym.x = y0.x * A0 + y1.x * A1;
        ym.y = y0.y * A0 + y1.y * A1;
        ym.z = y0.z * A0 + y1.z * A1;
        ym.w = y0.w * A0 + y1.w * A1;
        st4(&Ys2[row * 128 + (kc ^ (row & 7)) * 4], ym);
    }
    __syncthreads();

    const int q  = tid & 15;
    const int tj = tid >> 4;

    float4 acc[4];
#pragma unroll
    for (int a = 0; a < 4; ++a) acc[a] = make_float4(0.f, 0.f, 0.f, 0.f);
#pragma unroll 4
    for (int g = 0; g < 32; ++g) {
        float4 yv[4], wv[4];
#pragma unroll
        for (int a = 0; a < 4; ++a) {
            int r = q + 16 * a;
            yv[a] = ld4(&Ys2[r * 128 + (g ^ (r & 7)) * 4]);
        }
#pragma unroll
        for (int jj = 0; jj < 4; ++jj) {
            int cj = 4 * tj + jj;
            wv[jj] = ld4(&Ws2[cj * 128 + (g ^ (cj & 7)) * 4]);
        }
#pragma unroll
        for (int a = 0; a < 4; ++a) {
            acc[a].x += dot4(yv[a], wv[0]);
            acc[a].y += dot4(yv[a], wv[1]);
            acc[a].z += dot4(yv[a], wv[2]);
            acc[a].w += dot4(yv[a], wv[3]);
        }
    }

    float4 bz4 = ld4(&bz[o0 + 4 * tj]);
    float s = 0.f, s2 = 0.f;
#pragma unroll
    for (int a = 0; a < 4; ++a) {
        int n = n0 + q + 16 * a;
        float v0 = acc[a].x + bz4.x;
        float v1 = acc[a].y + bz4.y;
        float v2 = acc[a].z + bz4.z;
        float v3 = acc[a].w + bz4.w;
        Z[(size_t)(b * CINC + o0 + 4 * tj + 0) * NS + n] = v0;
        Z[(size_t)(b * CINC + o0 + 4 * tj + 1) * NS + n] = v1;
        Z[(size_t)(b * CINC + o0 + 4 * tj + 2) * NS + n] = v2;
        Z[(size_t)(b * CINC + o0 + 4 * tj + 3) * NS + n] = v3;
        s  += v0 + v1 + v2 + v3;
        s2 += v0 * v0 + v1 * v1 + v2 * v2 + v3 * v3;
    }
#pragma unroll
    for (int off = 1; off < 64; off <<= 1) {
        s  += __shfl_xor(s, off);
        s2 += __shfl_xor(s2, off);
    }
    if ((tid & 63) == 0) { red[(tid >> 6) * 2] = s; red[(tid >> 6) * 2 + 1] = s2; }
    __syncthreads();
    if (tid == 0) {
        float ts  = red[0] + red[2] + red[4] + red[6];
        float ts2 = red[1] + red[3] + red[5] + red[7];
        int pidx = b * 256 + ot * 64 + blockIdx.x;
        partials[pidx * 2 + 0] = ts;
        partials[pidx * 2 + 1] = ts2;
    }
}

// ---------------------------------------------------------------------------
// Kernel 4: reduce partials -> per-batch (mean, rstd).
// ---------------------------------------------------------------------------
__global__ void ln_stats_kernel(const float* __restrict__ partials,
                                float* __restrict__ stats)
{
    const int b = blockIdx.x;
    const int t = threadIdx.x;  // 64
    float s = 0.f, s2 = 0.f;
#pragma unroll
    for (int u = 0; u < 4; ++u) {
        const float* pp = &partials[(size_t)(b * 256 + t + 64 * u) * 2];
        s  += pp[0];
        s2 += pp[1];
    }
#pragma unroll
    for (int off = 1; off < 64; off <<= 1) {
        s  += __shfl_xor(s, off);
        s2 += __shfl_xor(s2, off);
    }
    if (t == 0) {
        const float M = 1048576.f;
        float mean = s / M;
        float var  = s2 / M - mean * mean;
        stats[b * 2 + 0] = mean;
        stats[b * 2 + 1] = rsqrtf(var + LN_EPS);
    }
}

// ---------------------------------------------------------------------------
// Kernel 5: out = (z - mean)*rstd*gamma + beta + x
// ---------------------------------------------------------------------------
__global__ __launch_bounds__(256) void final_kernel(
    const float* __restrict__ Z, const float* __restrict__ x,
    const float* __restrict__ gamma, const float* __restrict__ beta,
    const float* __restrict__ stats, float* __restrict__ out)
{
    const int total4 = BB * CINC * NS / 4;
    for (int i4 = blockIdx.x * 256 + threadIdx.x; i4 < total4;
         i4 += gridDim.x * 256) {
        int b  = i4 >> 18;
        int r4 = i4 & ((1 << 18) - 1);
        float mean = stats[b * 2 + 0];
        float rstd = stats[b * 2 + 1];
        float4 zv = ld4(&Z[(size_t)i4 * 4]);
        float4 xv = ld4(&x[(size_t)i4 * 4]);
        float4 gv = ld4(&gamma[(size_t)r4 * 4]);
        float4 bv = ld4(&beta[(size_t)r4 * 4]);
        float4 o;
        o.x = (zv.x - mean) * rstd * gv.x + bv.x + xv.x;
        o.y = (zv.y - mean) * rstd * gv.y + bv.y + xv.y;
        o.z = (zv.z - mean) * rstd * gv.z + bv.z + xv.z;
        o.w = (zv.w - mean) * rstd * gv.w + bv.w + xv.w;
        st4(&out[(size_t)i4 * 4], o);
    }
}

extern "C" void kernel_launch(void* const* d_in, const int* in_sizes, int n_in,
                              void* d_out, int out_size, void* d_ws, size_t ws_size,
                              hipStream_t stream)
{
    const float* x     = (const float*)d_in[0];
    const float* Wg    = (const float*)d_in[1];
    const float* bg    = (const float*)d_in[2];
    const float* Wt    = (const float*)d_in[3];
    const float* bt    = (const float*)d_in[4];
    const float* Wp    = (const float*)d_in[5];
    const float* bp    = (const float*)d_in[6];
    const float* Wz    = (const float*)d_in[7];
    const float* bz    = (const float*)d_in[8];
    const float* gamma = (const float*)d_in[9];
    const float* beta  = (const float*)d_in[10];
    float* out = (float*)d_out;

    // workspace: Qhi,Qlo,Khi,Klo,Vt bf16 (5 x 4MB = 20MB); Yp fp32 [2][B][N][C]
    // (16MB); ML (256KB); partials/stats. Z (16MB fp32) ALIASES Qhi..Klo,
    // which are dead once attn completes (stream-ordered). Total ~36.3MB.
    char* p = (char*)d_ws;
    const size_t SZH = (size_t)BB * NS * CCH * sizeof(ushort_t);  // 4 MB
    ushort_t* Qhi = (ushort_t*)p; p += SZH;
    ushort_t* Qlo = (ushort_t*)p; p += SZH;
    ushort_t* Khi = (ushort_t*)p; p += SZH;
    ushort_t* Klo = (ushort_t*)p; p += SZH;
    ushort_t* Vt  = (ushort_t*)p; p += SZH;
    float* Yp = (float*)p; p += (size_t)2 * BB * NS * CCH * sizeof(float);
    float* ML = (float*)p; p += (size_t)2 * BB * NS * 2 * sizeof(float);
    float* partials = (float*)p; p += BB * 256 * 2 * sizeof(float);
    float* stats    = (float*)p;
    float* Z = (float*)d_ws;   // alias Qhi..Klo (16MB), dead after attn

    proj_kernel<<<dim3(64, 6, BB), 256, 0, stream>>>(x, Wt, bt, Wp, bp, Wg, bg,
                                                     Qhi, Qlo, Khi, Klo, Vt);
    attn_kernel<<<dim3(64, 2, BB), 256, 0, stream>>>(Qhi, Qlo, Khi, Klo, Vt,
                                                     Yp, ML);
    zgemm_kernel<<<dim3(64, 4, BB), 256, 0, stream>>>(Yp, ML, Wz, bz, Z, partials);
    ln_stats_kernel<<<dim3(BB), 64, 0, stream>>>(partials, stats);
    final_kernel<<<dim3(2048), 256, 0, stream>>>(Z, x, gamma, beta, stats, out);
}

// Round 4
// 207.259 us; speedup vs baseline: 4.7862x; 1.7099x over previous
//
#include <hip/hip_runtime.h>
#include <hip/hip_bf16.h>

// NonLocalBlock for MI355X. B=4, CIN=256, C=128, H=W=64 -> N=4096.
// proj (fp32 -> bf16-split Q/K, pre-swizzled K-hi & V^T layouts) ->
// MFMA flash attention (KV-split 2, global_load_lds pipelined, coalesced epi)
// -> z-gemm fp32 (+merge, +LN partials) -> stats -> LN+residual.

#define BB   4
#define CINC 256
#define CCH  128
#define NS   4096
#define LN_EPS 1e-5f

typedef unsigned short ushort_t;
typedef unsigned int   uint_t;
typedef __bf16 bf16x8 __attribute__((ext_vector_type(8)));
typedef float  f32x4  __attribute__((ext_vector_type(4)));

typedef const __attribute__((address_space(1))) void* gas_ptr;
typedef __attribute__((address_space(3))) void*       las_ptr;

__device__ __forceinline__ void gload16(const ushort_t* g, ushort_t* l) {
    __builtin_amdgcn_global_load_lds((gas_ptr)g, (las_ptr)l, 16, 0, 0);
}

__device__ __forceinline__ float4 ld4(const float* p) { return *reinterpret_cast<const float4*>(p); }
__device__ __forceinline__ void   st4(float* p, float4 v) { *reinterpret_cast<float4*>(p) = v; }

__device__ __forceinline__ ushort_t f2bf(float f) {
    __hip_bfloat16 h = __float2bfloat16(f);
    return *reinterpret_cast<ushort_t*>(&h);
}
__device__ __forceinline__ float bf2f(ushort_t u) {
    __hip_bfloat16 h = *reinterpret_cast<__hip_bfloat16*>(&u);
    return __bfloat162float(h);
}

#define FMA4(acc, s, v)                                                        \
    do {                                                                       \
        (acc).x += (s) * (v).x;                                                \
        (acc).y += (s) * (v).y;                                                \
        (acc).z += (s) * (v).z;                                                \
        (acc).w += (s) * (v).w;                                                \
    } while (0)

__device__ __forceinline__ float dot4(float4 a, float4 b) {
    return a.x * b.x + a.y * b.y + a.z * b.z + a.w * b.w;
}

// ---------------------------------------------------------------------------
// Kernel 1: fused projection GEMM (fp32 compute).
// mid 0: theta->Qhi/Qlo (linear [B][N][C]); mid 1: phi->Khi (chunk-swizzled
// rows)/Klo (linear); mid 2: g->Vt ([B][C][N], key-chunk swizzled).
// ---------------------------------------------------------------------------
__global__ __launch_bounds__(256) void proj_kernel(
    const float* __restrict__ x,
    const float* __restrict__ Wt, const float* __restrict__ bt,
    const float* __restrict__ Wp, const float* __restrict__ bp,
    const float* __restrict__ Wg, const float* __restrict__ bg,
    ushort_t* __restrict__ Qhi, ushort_t* __restrict__ Qlo,
    ushort_t* __restrict__ KhiS, ushort_t* __restrict__ Klo,
    ushort_t* __restrict__ VtS)
{
    __shared__ float Ws[64 * 64];
    __shared__ float Xs[64 * 68];   // reused as transpose buffer T[64][68]

    const int tid = threadIdx.x;
    const int b   = blockIdx.z;
    const int rt  = blockIdx.y;          // 0..5
    const int n0  = blockIdx.x * 64;
    const int mid = rt >> 1;
    const int sub = (rt & 1) * 64;

    const float* Wsel = (mid == 0) ? Wt : (mid == 1) ? Wp : Wg;
    const float* bsel = (mid == 0) ? bt : (mid == 1) ? bp : bg;

    const int q  = tid & 15;
    const int tj = tid >> 4;

    float4 acc[4];
#pragma unroll
    for (int a = 0; a < 4; ++a) acc[a] = make_float4(0.f, 0.f, 0.f, 0.f);

    for (int kb = 0; kb < 4; ++kb) {
#pragma unroll
        for (int u = 0; u < 4; ++u) {
            int fi = tid + 256 * u;
            int row = fi >> 4;
            int kc  = fi & 15;
            float4 v = ld4(&Wsel[(size_t)(sub + row) * CINC + kb * 64 + kc * 4]);
            st4(&Ws[row * 64 + (kc ^ (row & 7)) * 4], v);
        }
#pragma unroll
        for (int u = 0; u < 4; ++u) {
            int fi = tid + 256 * u;
            int k  = fi >> 4;
            int nc = fi & 15;
            float4 v = ld4(&x[(size_t)(b * CINC + kb * 64 + k) * NS + n0 + nc * 4]);
            st4(&Xs[k * 68 + nc * 4], v);
        }
        __syncthreads();

#pragma unroll 4
        for (int g = 0; g < 16; ++g) {
            float4 wv[4], xv[4];
#pragma unroll
            for (int a = 0; a < 4; ++a) {
                int r = q + 16 * a;
                wv[a] = ld4(&Ws[r * 64 + ((g ^ (r & 7)) & 15) * 4]);
            }
#pragma unroll
            for (int k2 = 0; k2 < 4; ++k2)
                xv[k2] = ld4(&Xs[(g * 4 + k2) * 68 + tj * 4]);
#pragma unroll
            for (int a = 0; a < 4; ++a) {
                FMA4(acc[a], wv[a].x, xv[0]);
                FMA4(acc[a], wv[a].y, xv[1]);
                FMA4(acc[a], wv[a].z, xv[2]);
                FMA4(acc[a], wv[a].w, xv[3]);
            }
        }
        __syncthreads();
    }

    if (mid == 2) {
        // V^T: key-chunk-swizzled layout so attn can global_load_lds linearly.
#pragma unroll
        for (int a = 0; a < 4; ++a) {
            int c = sub + q + 16 * a;
            float bias = bsel[c];
            ushort4 v4;
            v4.x = f2bf(acc[a].x + bias);
            v4.y = f2bf(acc[a].y + bias);
            v4.z = f2bf(acc[a].z + bias);
            v4.w = f2bf(acc[a].w + bias);
            int p_  = (tj >> 1) ^ (c & 7);          // swizzled 8-key chunk
            int nsw = n0 + p_ * 8 + ((4 * tj) & 7);
            *reinterpret_cast<ushort4*>(&VtS[(size_t)(b * CCH + c) * NS + nsw]) = v4;
        }
    } else {
        ushort_t* H = (mid == 0) ? Qhi : KhiS;
        ushort_t* L = (mid == 0) ? Qlo : Klo;
        float* T = Xs;   // [64 n][stride 68] transpose buffer
#pragma unroll
        for (int a = 0; a < 4; ++a) {
            float bias = bsel[sub + q + 16 * a];
            T[(4 * tj + 0) * 68 + q + 16 * a] = acc[a].x + bias;
            T[(4 * tj + 1) * 68 + q + 16 * a] = acc[a].y + bias;
            T[(4 * tj + 2) * 68 + q + 16 * a] = acc[a].z + bias;
            T[(4 * tj + 3) * 68 + q + 16 * a] = acc[a].w + bias;
        }
        __syncthreads();
#pragma unroll
        for (int u = 0; u < 2; ++u) {
            int task = u * 256 + tid;
            int n  = task >> 3;
            int j  = task & 7;
            int c0 = j * 8;
            float4 lo4 = ld4(&T[n * 68 + c0]);
            float4 hi4 = ld4(&T[n * 68 + c0 + 4]);
            float v[8] = {lo4.x, lo4.y, lo4.z, lo4.w, hi4.x, hi4.y, hi4.z, hi4.w};
            uint_t hw[4], lw[4];
#pragma unroll
            for (int jj = 0; jj < 4; ++jj) {
                ushort_t h0 = f2bf(v[2 * jj]);
                ushort_t h1 = f2bf(v[2 * jj + 1]);
                ushort_t e0 = f2bf(v[2 * jj] - bf2f(h0));
                ushort_t e1 = f2bf(v[2 * jj + 1] - bf2f(h1));
                hw[jj] = (uint_t)h0 | ((uint_t)h1 << 16);
                lw[jj] = (uint_t)e0 | ((uint_t)e1 << 16);
            }
            size_t rowbase = (size_t)(b * NS + n0 + n) * CCH;
            int jsw = (mid == 1) ? (j ^ (n & 7)) : j;   // swizzle K-hi only
            *reinterpret_cast<uint4*>(&H[rowbase + sub + jsw * 8]) =
                make_uint4(hw[0], hw[1], hw[2], hw[3]);
            *reinterpret_cast<uint4*>(&L[rowbase + sub + j * 8]) =
                make_uint4(lw[0], lw[1], lw[2], lw[3]);
        }
    }
}

// ---------------------------------------------------------------------------
// Kernel 2: MFMA flash attention, KV-split 2, global_load_lds pipelined.
// LDS 72KB: Kh dbuf (2x16K) | V (16K) | Kl (16K) | P (8K). 2 blocks/CU.
// ---------------------------------------------------------------------------
__global__ __launch_bounds__(256) void attn_kernel(
    const ushort_t* __restrict__ Qhi, const ushort_t* __restrict__ Qlo,
    const ushort_t* __restrict__ KhiS, const ushort_t* __restrict__ Klo,
    const ushort_t* __restrict__ VtS, float* __restrict__ Yp,
    float* __restrict__ ML)
{
    __shared__ __align__(16) char smem[73728];
    ushort_t* Kh0 = (ushort_t*)smem;
    ushort_t* Kh1 = (ushort_t*)(smem + 16384);
    ushort_t* Vl  = (ushort_t*)(smem + 32768);
    ushort_t* Kl  = (ushort_t*)(smem + 49152);
    ushort_t* Pl  = (ushort_t*)(smem + 65536);
    float*    stage = (float*)smem;          // epilogue reuse [64][132]

    const int tid  = threadIdx.x;
    const int w    = tid >> 6;
    const int lane = tid & 63;
    const int lq   = lane & 15;
    const int g    = lane >> 4;
    const int n0   = blockIdx.x * 64;
    const int h    = blockIdx.y;    // KV half
    const int b    = blockIdx.z;

    // Q fragments in registers (linear layout)
    bf16x8 qh[4], ql[4];
    {
        const ushort_t* qbh = Qhi + (size_t)(b * NS + n0 + w * 16 + lq) * CCH;
        const ushort_t* qbl = Qlo + (size_t)(b * NS + n0 + w * 16 + lq) * CCH;
#pragma unroll
        for (int cs = 0; cs < 4; ++cs) {
            qh[cs] = *reinterpret_cast<const bf16x8*>(qbh + cs * 32 + g * 8);
            ql[cs] = *reinterpret_cast<const bf16x8*>(qbl + cs * 32 + g * 8);
        }
    }

    f32x4 yacc[8];
#pragma unroll
    for (int cf = 0; cf < 8; ++cf) yacc[cf] = (f32x4){0.f, 0.f, 0.f, 0.f};
    float m_run = -1e30f, l_run = 0.f;

    const ushort_t* Khg = KhiS + (size_t)b * NS * CCH;
    const ushort_t* Klg = Klo + (size_t)b * NS * CCH;
    const ushort_t* Vtg = VtS + (size_t)b * CCH * NS;

    const int NT = 32;
    const int ktbase = h * 32;

    uint4 tL[4];
    auto load_kl = [&](int ktg) {
        const int m0 = ktg * 64;
#pragma unroll
        for (int it = 0; it < 4; ++it) {
            int fi = it * 256 + tid;
            int kr = fi >> 4;
            int cc = fi & 15;
            tL[it] = *reinterpret_cast<const uint4*>(Klg + (size_t)(m0 + kr) * CCH + cc * 8);
        }
    };
    auto write_kl = [&]() {
#pragma unroll
        for (int it = 0; it < 4; ++it) {
            int fi = it * 256 + tid;
            int kr = fi >> 4;
            int cc = fi & 15;
            int swz = (cc & 8) | ((cc & 7) ^ (kr & 7));
            *reinterpret_cast<uint4*>(&Kl[kr * 128 + swz * 8]) = tL[it];
        }
    };
    auto gload_kh = [&](int ktg, ushort_t* dst) {
        const ushort_t* base = Khg + (size_t)(ktg * 64) * CCH;  // contiguous 16KB
#pragma unroll
        for (int i = 0; i < 4; ++i) {
            int off = i * 2048 + tid * 8;   // ushorts
            gload16(base + off, dst + off);
        }
    };
    auto gload_v = [&](int ktg) {
        const int m0 = ktg * 64;            // key column offset (ushorts)
#pragma unroll
        for (int i = 0; i < 4; ++i) {
            int o  = i * 2048 + tid * 8;    // ushort offset in 8K-ushort tile
            int cr = o >> 6;                // channel row 0..127
            int cw = o & 63;                // within-row ushort 0..63
            gload16(Vtg + (size_t)cr * NS + m0 + cw, Vl + o);
        }
    };

    // prologue: tile 0
    gload_kh(ktbase, Kh0);
    load_kl(ktbase);
    write_kl();
    __syncthreads();   // drains vmcnt: Kh0 + Kl ready

    for (int kt = 0; kt < NT; ++kt) {
        ushort_t* KhCur = (kt & 1) ? Kh1 : Kh0;
        ushort_t* KhNxt = (kt & 1) ? Kh0 : Kh1;
        const bool more = (kt + 1 < NT);

        gload_v(ktbase + kt);                     // V(t), needed after B1
        if (more) {
            gload_kh(ktbase + kt + 1, KhNxt);     // K-hi(t+1)
            load_kl(ktbase + kt + 1);             // K-lo(t+1) -> regs
        }

        // ---- QK^T: T[k=16kk+4g+r][q=lq] via 3-pass split
        f32x4 tacc[4];
#pragma unroll
        for (int kk = 0; kk < 4; ++kk) tacc[kk] = (f32x4){0.f, 0.f, 0.f, 0.f};
        __builtin_amdgcn_s_setprio(1);
#pragma unroll
        for (int cs = 0; cs < 4; ++cs) {
#pragma unroll
            for (int kk = 0; kk < 4; ++kk) {
                int kr = kk * 16 + lq;
                int cc = g + 4 * cs;
                int swz = (cc & 8) | ((cc & 7) ^ (kr & 7));
                bf16x8 ah = *reinterpret_cast<const bf16x8*>(&KhCur[kr * 128 + swz * 8]);
                bf16x8 al = *reinterpret_cast<const bf16x8*>(&Kl[kr * 128 + swz * 8]);
                tacc[kk] = __builtin_amdgcn_mfma_f32_16x16x32_bf16(ah, qh[cs], tacc[kk], 0, 0, 0);
                tacc[kk] = __builtin_amdgcn_mfma_f32_16x16x32_bf16(al, qh[cs], tacc[kk], 0, 0, 0);
                tacc[kk] = __builtin_amdgcn_mfma_f32_16x16x32_bf16(ah, ql[cs], tacc[kk], 0, 0, 0);
            }
        }
        __builtin_amdgcn_s_setprio(0);

        // ---- online softmax (lane holds 16 keys of row q=lq)
        float mx = -1e30f;
#pragma unroll
        for (int kk = 0; kk < 4; ++kk)
#pragma unroll
            for (int r = 0; r < 4; ++r) mx = fmaxf(mx, tacc[kk][r]);
        mx = fmaxf(mx, __shfl_xor(mx, 16));
        mx = fmaxf(mx, __shfl_xor(mx, 32));
        float m_new = fmaxf(m_run, mx);
        float alpha = __expf(m_run - m_new);
        float pr[4][4];
        float psum = 0.f;
#pragma unroll
        for (int kk = 0; kk < 4; ++kk)
#pragma unroll
            for (int r = 0; r < 4; ++r) {
                float v = __expf(tacc[kk][r] - m_new);
                pr[kk][r] = v;
                psum += v;
            }
        psum += __shfl_xor(psum, 16);
        psum += __shfl_xor(psum, 32);
        l_run = l_run * alpha + psum;
        m_run = m_new;

        // ---- pack P to bf16, wave-local swizzled LDS round trip
#pragma unroll
        for (int kk = 0; kk < 4; ++kk) {
            uint_t lo = (uint_t)f2bf(pr[kk][0]) | ((uint_t)f2bf(pr[kk][1]) << 16);
            uint_t hi = (uint_t)f2bf(pr[kk][2]) | ((uint_t)f2bf(pr[kk][3]) << 16);
            int kbase = kk * 16 + 4 * g;
            int swz = (kbase >> 3) ^ (lq & 7);
            uint2 val = make_uint2(lo, hi);
            *reinterpret_cast<uint2*>(&Pl[w * 1024 + lq * 64 + swz * 8 + (kbase & 7)]) = val;
        }
        bf16x8 pa[2];
#pragma unroll
        for (int s = 0; s < 2; ++s) {
            int swz = (g + 4 * s) ^ (lq & 7);
            pa[s] = *reinterpret_cast<const bf16x8*>(&Pl[w * 1024 + lq * 64 + swz * 8]);
        }

        __syncthreads();   // B1: V(t)/Kh(t+1) landed; all Kl(t) reads done
        if (more) write_kl();   // Kl(t+1) from regs

        // ---- rescale Y by alpha(q=4g+r), then Y += P V
        float a0 = __shfl(alpha, 4 * g + 0);
        float a1 = __shfl(alpha, 4 * g + 1);
        float a2 = __shfl(alpha, 4 * g + 2);
        float a3 = __shfl(alpha, 4 * g + 3);
#pragma unroll
        for (int cf = 0; cf < 8; ++cf) {
            yacc[cf][0] *= a0;
            yacc[cf][1] *= a1;
            yacc[cf][2] *= a2;
            yacc[cf][3] *= a3;
        }
        __builtin_amdgcn_s_setprio(1);
#pragma unroll
        for (int cf = 0; cf < 8; ++cf) {
            int c = cf * 16 + lq;
#pragma unroll
            for (int s = 0; s < 2; ++s) {
                int swz = (g + 4 * s) ^ (c & 7);
                bf16x8 vb = *reinterpret_cast<const bf16x8*>(&Vl[c * 64 + swz * 8]);
                yacc[cf] = __builtin_amdgcn_mfma_f32_16x16x32_bf16(pa[s], vb, yacc[cf], 0, 0, 0);
            }
        }
        __builtin_amdgcn_s_setprio(0);

        __syncthreads();   // B2: PV reads of Vl done; Kl(t+1) visible
    }

    // ---- epilogue: coalesced unnormalized-Y store via LDS stage
#pragma unroll
    for (int cf = 0; cf < 8; ++cf)
#pragma unroll
        for (int r = 0; r < 4; ++r)
            stage[(w * 16 + 4 * g + r) * 132 + cf * 16 + lq] = yacc[cf][r];
    __syncthreads();
    float* Ybase = Yp + ((size_t)(h * BB + b) * NS + n0) * CCH;
#pragma unroll
    for (int u = 0; u < 8; ++u) {
        int idx = u * 256 + tid;
        int row = idx >> 5;
        int c4  = idx & 31;
        float4 v = ld4(&stage[row * 132 + c4 * 4]);
        st4(&Ybase[(size_t)row * CCH + c4 * 4], v);
    }
    if (g == 0) {
        size_t mi = ((size_t)(h * BB + b) * NS + n0 + w * 16 + lq) * 2;
        ML[mi + 0] = m_run;
        ML[mi + 1] = l_run;
    }
}

// ---------------------------------------------------------------------------
// Kernel 3: z = Wz . Y + bz (fp32) with on-the-fly merge of the two attention
// halves, plus deterministic LN partial sums.
// ---------------------------------------------------------------------------
__global__ __launch_bounds__(256) void zgemm_kernel(
    const float* __restrict__ Yp, const float* __restrict__ ML,
    const float* __restrict__ Wz, const float* __restrict__ bz,
    float* __restrict__ Z, float* __restrict__ partials)
{
    __shared__ float Ws2[64 * 128];
    __shared__ float Ys2[64 * 128];
    __shared__ float a01[64][2];
    __shared__ float red[8];

    const int tid = threadIdx.x;
    const int b   = blockIdx.z;
    const int ot  = blockIdx.y;
    const int n0  = blockIdx.x * 64;
    const int o0  = ot * 64;

    const float* Y0 = Yp + (size_t)(0 * BB + b) * NS * CCH;
    const float* Y1 = Yp + (size_t)(1 * BB + b) * NS * CCH;

    if (tid < 64) {
        int n = n0 + tid;
        float m0 = ML[((size_t)(0 * BB + b) * NS + n) * 2 + 0];
        float l0 = ML[((size_t)(0 * BB + b) * NS + n) * 2 + 1];
        float m1 = ML[((size_t)(1 * BB + b) * NS + n) * 2 + 0];
        float l1 = ML[((size_t)(1 * BB + b) * NS + n) * 2 + 1];
        float m  = fmaxf(m0, m1);
        float w0 = __expf(m0 - m), w1 = __expf(m1 - m);
        float inv = 1.0f / (l0 * w0 + l1 * w1);
        a01[tid][0] = w0 * inv;
        a01[tid][1] = w1 * inv;
    }
    __syncthreads();

#pragma unroll
    for (int u = 0; u < 8; ++u) {
        int fi = tid + 256 * u;
        int row = fi >> 5;
        int kc  = fi & 31;
        st4(&Ws2[row * 128 + (kc ^ (row & 7)) * 4],
            ld4(&Wz[(size_t)(o0 + row) * CCH + kc * 4]));
        float4 y0 = ld4(&Y0[(size_t)(n0 + row) * CCH + kc * 4]);
        float4 y1 = ld4(&Y1[(size_t)(n0 + row) * CCH + kc * 4]);
        float A0 = a01[row][0], A1 = a01[row][1];
        float4 ym;
        ym.x = y0.x * A0 + y1.x * A1;
        ym.y = y0.y * A0 + y1.y * A1;
        ym.z = y0.z * A0 + y1.z * A1;
        ym.w = y0.w * A0 + y1.w * A1;
        st4(&Ys2[row * 128 + (kc ^ (row & 7)) * 4], ym);
    }
    __syncthreads();

    const int q  = tid & 15;
    const int tj = tid >> 4;

    float4 acc[4];
#pragma unroll
    for (int a = 0; a < 4; ++a) acc[a] = make_float4(0.f, 0.f, 0.f, 0.f);
#pragma unroll 4
    for (int g = 0; g < 32; ++g) {
        float4 yv[4], wv[4];
#pragma unroll
        for (int a = 0; a < 4; ++a) {
            int r = q + 16 * a;
            yv[a] = ld4(&Ys2[r * 128 + (g ^ (r & 7)) * 4]);
        }
#pragma unroll
        for (int jj = 0; jj < 4; ++jj) {
            int cj = 4 * tj + jj;
            wv[jj] = ld4(&Ws2[cj * 128 + (g ^ (cj & 7)) * 4]);
        }
#pragma unroll
        for (int a = 0; a < 4; ++a) {
            acc[a].x += dot4(yv[a], wv[0]);
            acc[a].y += dot4(yv[a], wv[1]);
            acc[a].z += dot4(yv[a], wv[2]);
            acc[a].w += dot4(yv[a], wv[3]);
        }
    }

    float4 bz4 = ld4(&bz[o0 + 4 * tj]);
    float s = 0.f, s2 = 0.f;
#pragma unroll
    for (int a = 0; a < 4; ++a) {
        int n = n0 + q + 16 * a;
        float v0 = acc[a].x + bz4.x;
        float v1 = acc[a].y + bz4.y;
        float v2 = acc[a].z + bz4.z;
        float v3 = acc[a].w + bz4.w;
        Z[(size_t)(b * CINC + o0 + 4 * tj + 0) * NS + n] = v0;
        Z[(size_t)(b * CINC + o0 + 4 * tj + 1) * NS + n] = v1;
        Z[(size_t)(b * CINC + o0 + 4 * tj + 2) * NS + n] = v2;
        Z[(size_t)(b * CINC + o0 + 4 * tj + 3) * NS + n] = v3;
        s  += v0 + v1 + v2 + v3;
        s2 += v0 * v0 + v1 * v1 + v2 * v2 + v3 * v3;
    }
#pragma unroll
    for (int off = 1; off < 64; off <<= 1) {
        s  += __shfl_xor(s, off);
        s2 += __shfl_xor(s2, off);
    }
    if ((tid & 63) == 0) { red[(tid >> 6) * 2] = s; red[(tid >> 6) * 2 + 1] = s2; }
    __syncthreads();
    if (tid == 0) {
        float ts  = red[0] + red[2] + red[4] + red[6];
        float ts2 = red[1] + red[3] + red[5] + red[7];
        int pidx = b * 256 + ot * 64 + blockIdx.x;
        partials[pidx * 2 + 0] = ts;
        partials[pidx * 2 + 1] = ts2;
    }
}

// ---------------------------------------------------------------------------
// Kernel 4: reduce partials -> per-batch (mean, rstd).
// ---------------------------------------------------------------------------
__global__ void ln_stats_kernel(const float* __restrict__ partials,
                                float* __restrict__ stats)
{
    const int b = blockIdx.x;
    const int t = threadIdx.x;  // 64
    float s = 0.f, s2 = 0.f;
#pragma unroll
    for (int u = 0; u < 4; ++u) {
        const float* pp = &partials[(size_t)(b * 256 + t + 64 * u) * 2];
        s  += pp[0];
        s2 += pp[1];
    }
#pragma unroll
    for (int off = 1; off < 64; off <<= 1) {
        s  += __shfl_xor(s, off);
        s2 += __shfl_xor(s2, off);
    }
    if (t == 0) {
        const float M = 1048576.f;
        float mean = s / M;
        float var  = s2 / M - mean * mean;
        stats[b * 2 + 0] = mean;
        stats[b * 2 + 1] = rsqrtf(var + LN_EPS);
    }
}

// ---------------------------------------------------------------------------
// Kernel 5: out = (z - mean)*rstd*gamma + beta + x
// ---------------------------------------------------------------------------
__global__ __launch_bounds__(256) void final_kernel(
    const float* __restrict__ Z, const float* __restrict__ x,
    const float* __restrict__ gamma, const float* __restrict__ beta,
    const float* __restrict__ stats, float* __restrict__ out)
{
    const int total4 = BB * CINC * NS / 4;
    for (int i4 = blockIdx.x * 256 + threadIdx.x; i4 < total4;
         i4 += gridDim.x * 256) {
        int b  = i4 >> 18;
        int r4 = i4 & ((1 << 18) - 1);
        float mean = stats[b * 2 + 0];
        float rstd = stats[b * 2 + 1];
        float4 zv = ld4(&Z[(size_t)i4 * 4]);
        float4 xv = ld4(&x[(size_t)i4 * 4]);
        float4 gv = ld4(&gamma[(size_t)r4 * 4]);
        float4 bv = ld4(&beta[(size_t)r4 * 4]);
        float4 o;
        o.x = (zv.x - mean) * rstd * gv.x + bv.x + xv.x;
        o.y = (zv.y - mean) * rstd * gv.y + bv.y + xv.y;
        o.z = (zv.z - mean) * rstd * gv.z + bv.z + xv.z;
        o.w = (zv.w - mean) * rstd * gv.w + bv.w + xv.w;
        st4(&out[(size_t)i4 * 4], o);
    }
}

extern "C" void kernel_launch(void* const* d_in, const int* in_sizes, int n_in,
                              void* d_out, int out_size, void* d_ws, size_t ws_size,
                              hipStream_t stream)
{
    const float* x     = (const float*)d_in[0];
    const float* Wg    = (const float*)d_in[1];
    const float* bg    = (const float*)d_in[2];
    const float* Wt    = (const float*)d_in[3];
    const float* bt    = (const float*)d_in[4];
    const float* Wp    = (const float*)d_in[5];
    const float* bp    = (const float*)d_in[6];
    const float* Wz    = (const float*)d_in[7];
    const float* bz    = (const float*)d_in[8];
    const float* gamma = (const float*)d_in[9];
    const float* beta  = (const float*)d_in[10];
    float* out = (float*)d_out;

    // workspace: Qhi,Qlo,KhiS,Klo,VtS bf16 (5 x 4MB); Yp fp32 [2][B][N][C]
    // (16MB); ML; partials/stats. Z (16MB) aliases Qhi..Klo (dead after attn).
    char* p = (char*)d_ws;
    const size_t SZH = (size_t)BB * NS * CCH * sizeof(ushort_t);  // 4 MB
    ushort_t* Qhi  = (ushort_t*)p; p += SZH;
    ushort_t* Qlo  = (ushort_t*)p; p += SZH;
    ushort_t* KhiS = (ushort_t*)p; p += SZH;
    ushort_t* Klo  = (ushort_t*)p; p += SZH;
    ushort_t* VtS  = (ushort_t*)p; p += SZH;
    float* Yp = (float*)p; p += (size_t)2 * BB * NS * CCH * sizeof(float);
    float* ML = (float*)p; p += (size_t)2 * BB * NS * 2 * sizeof(float);
    float* partials = (float*)p; p += BB * 256 * 2 * sizeof(float);
    float* stats    = (float*)p;
    float* Z = (float*)d_ws;   // alias Qhi..Klo (16MB), dead after attn

    proj_kernel<<<dim3(64, 6, BB), 256, 0, stream>>>(x, Wt, bt, Wp, bp, Wg, bg,
                                                     Qhi, Qlo, KhiS, Klo, VtS);
    attn_kernel<<<dim3(64, 2, BB), 256, 0, stream>>>(Qhi, Qlo, KhiS, Klo, VtS,
                                                     Yp, ML);
    zgemm_kernel<<<dim3(64, 4, BB), 256, 0, stream>>>(Yp, ML, Wz, bz, Z, partials);
    ln_stats_kernel<<<dim3(BB), 64, 0, stream>>>(partials, stats);
    final_kernel<<<dim3(2048), 256, 0, stream>>>(Z, x, gamma, beta, stats, out);
}

// Round 5
// 183.653 us; speedup vs baseline: 5.4014x; 1.1285x over previous
//
#include <hip/hip_runtime.h>
#include <hip/hip_bf16.h>

// NonLocalBlock for MI355X. B=4, CIN=256, C=128, H=W=64 -> N=4096.
// proj (fp32 -> bf16-split Q/K, pre-swizzled K-hi & V^T layouts) ->
// MFMA flash attention (QTILE=128, 8 waves, KV-split 4, global_load_lds
// pipelined, defer-max) -> merge -> z-gemm fp32 (+LN partials) -> stats ->
// LN+residual.

#define BB   4
#define CINC 256
#define CCH  128
#define NS   4096
#define LN_EPS 1e-5f

typedef unsigned short ushort_t;
typedef unsigned int   uint_t;
typedef __bf16 bf16x8 __attribute__((ext_vector_type(8)));
typedef float  f32x4  __attribute__((ext_vector_type(4)));

typedef const __attribute__((address_space(1))) void* gas_ptr;
typedef __attribute__((address_space(3))) void*       las_ptr;

__device__ __forceinline__ void gload16(const ushort_t* g, ushort_t* l) {
    __builtin_amdgcn_global_load_lds((gas_ptr)g, (las_ptr)l, 16, 0, 0);
}

__device__ __forceinline__ float4 ld4(const float* p) { return *reinterpret_cast<const float4*>(p); }
__device__ __forceinline__ void   st4(float* p, float4 v) { *reinterpret_cast<float4*>(p) = v; }

__device__ __forceinline__ ushort_t f2bf(float f) {
    __hip_bfloat16 h = __float2bfloat16(f);
    return *reinterpret_cast<ushort_t*>(&h);
}
__device__ __forceinline__ float bf2f(ushort_t u) {
    __hip_bfloat16 h = *reinterpret_cast<__hip_bfloat16*>(&u);
    return __bfloat162float(h);
}

#define FMA4(acc, s, v)                                                        \
    do {                                                                       \
        (acc).x += (s) * (v).x;                                                \
        (acc).y += (s) * (v).y;                                                \
        (acc).z += (s) * (v).z;                                                \
        (acc).w += (s) * (v).w;                                                \
    } while (0)

__device__ __forceinline__ float dot4(float4 a, float4 b) {
    return a.x * b.x + a.y * b.y + a.z * b.z + a.w * b.w;
}

// ---------------------------------------------------------------------------
// Kernel 1: fused projection GEMM (fp32 compute).
// mid 0: theta->Qhi/Qlo (linear [B][N][C]); mid 1: phi->Khi (chunk-swizzled
// rows)/Klo (linear); mid 2: g->Vt ([B][C][N], key-chunk swizzled).
// ---------------------------------------------------------------------------
__global__ __launch_bounds__(256) void proj_kernel(
    const float* __restrict__ x,
    const float* __restrict__ Wt, const float* __restrict__ bt,
    const float* __restrict__ Wp, const float* __restrict__ bp,
    const float* __restrict__ Wg, const float* __restrict__ bg,
    ushort_t* __restrict__ Qhi, ushort_t* __restrict__ Qlo,
    ushort_t* __restrict__ KhiS, ushort_t* __restrict__ Klo,
    ushort_t* __restrict__ VtS)
{
    __shared__ float Ws[64 * 64];
    __shared__ float Xs[64 * 68];   // reused as transpose buffer T[64][68]

    const int tid = threadIdx.x;
    const int b   = blockIdx.z;
    const int rt  = blockIdx.y;          // 0..5
    const int n0  = blockIdx.x * 64;
    const int mid = rt >> 1;
    const int sub = (rt & 1) * 64;

    const float* Wsel = (mid == 0) ? Wt : (mid == 1) ? Wp : Wg;
    const float* bsel = (mid == 0) ? bt : (mid == 1) ? bp : bg;

    const int q  = tid & 15;
    const int tj = tid >> 4;

    float4 acc[4];
#pragma unroll
    for (int a = 0; a < 4; ++a) acc[a] = make_float4(0.f, 0.f, 0.f, 0.f);

    for (int kb = 0; kb < 4; ++kb) {
#pragma unroll
        for (int u = 0; u < 4; ++u) {
            int fi = tid + 256 * u;
            int row = fi >> 4;
            int kc  = fi & 15;
            float4 v = ld4(&Wsel[(size_t)(sub + row) * CINC + kb * 64 + kc * 4]);
            st4(&Ws[row * 64 + (kc ^ (row & 7)) * 4], v);
        }
#pragma unroll
        for (int u = 0; u < 4; ++u) {
            int fi = tid + 256 * u;
            int k  = fi >> 4;
            int nc = fi & 15;
            float4 v = ld4(&x[(size_t)(b * CINC + kb * 64 + k) * NS + n0 + nc * 4]);
            st4(&Xs[k * 68 + nc * 4], v);
        }
        __syncthreads();

#pragma unroll 4
        for (int g = 0; g < 16; ++g) {
            float4 wv[4], xv[4];
#pragma unroll
            for (int a = 0; a < 4; ++a) {
                int r = q + 16 * a;
                wv[a] = ld4(&Ws[r * 64 + ((g ^ (r & 7)) & 15) * 4]);
            }
#pragma unroll
            for (int k2 = 0; k2 < 4; ++k2)
                xv[k2] = ld4(&Xs[(g * 4 + k2) * 68 + tj * 4]);
#pragma unroll
            for (int a = 0; a < 4; ++a) {
                FMA4(acc[a], wv[a].x, xv[0]);
                FMA4(acc[a], wv[a].y, xv[1]);
                FMA4(acc[a], wv[a].z, xv[2]);
                FMA4(acc[a], wv[a].w, xv[3]);
            }
        }
        __syncthreads();
    }

    if (mid == 2) {
        // V^T: key-chunk-swizzled layout so attn can global_load_lds linearly.
#pragma unroll
        for (int a = 0; a < 4; ++a) {
            int c = sub + q + 16 * a;
            float bias = bsel[c];
            ushort4 v4;
            v4.x = f2bf(acc[a].x + bias);
            v4.y = f2bf(acc[a].y + bias);
            v4.z = f2bf(acc[a].z + bias);
            v4.w = f2bf(acc[a].w + bias);
            int p_  = (tj >> 1) ^ (c & 7);          // swizzled 8-key chunk
            int nsw = n0 + p_ * 8 + ((4 * tj) & 7);
            *reinterpret_cast<ushort4*>(&VtS[(size_t)(b * CCH + c) * NS + nsw]) = v4;
        }
    } else {
        ushort_t* H = (mid == 0) ? Qhi : KhiS;
        ushort_t* L = (mid == 0) ? Qlo : Klo;
        float* T = Xs;   // [64 n][stride 68] transpose buffer
#pragma unroll
        for (int a = 0; a < 4; ++a) {
            float bias = bsel[sub + q + 16 * a];
            T[(4 * tj + 0) * 68 + q + 16 * a] = acc[a].x + bias;
            T[(4 * tj + 1) * 68 + q + 16 * a] = acc[a].y + bias;
            T[(4 * tj + 2) * 68 + q + 16 * a] = acc[a].z + bias;
            T[(4 * tj + 3) * 68 + q + 16 * a] = acc[a].w + bias;
        }
        __syncthreads();
#pragma unroll
        for (int u = 0; u < 2; ++u) {
            int task = u * 256 + tid;
            int n  = task >> 3;
            int j  = task & 7;
            int c0 = j * 8;
            float4 lo4 = ld4(&T[n * 68 + c0]);
            float4 hi4 = ld4(&T[n * 68 + c0 + 4]);
            float v[8] = {lo4.x, lo4.y, lo4.z, lo4.w, hi4.x, hi4.y, hi4.z, hi4.w};
            uint_t hw[4], lw[4];
#pragma unroll
            for (int jj = 0; jj < 4; ++jj) {
                ushort_t h0 = f2bf(v[2 * jj]);
                ushort_t h1 = f2bf(v[2 * jj + 1]);
                ushort_t e0 = f2bf(v[2 * jj] - bf2f(h0));
                ushort_t e1 = f2bf(v[2 * jj + 1] - bf2f(h1));
                hw[jj] = (uint_t)h0 | ((uint_t)h1 << 16);
                lw[jj] = (uint_t)e0 | ((uint_t)e1 << 16);
            }
            size_t rowbase = (size_t)(b * NS + n0 + n) * CCH;
            int jsw = (mid == 1) ? (j ^ (n & 7)) : j;   // swizzle K-hi only
            *reinterpret_cast<uint4*>(&H[rowbase + sub + jsw * 8]) =
                make_uint4(hw[0], hw[1], hw[2], hw[3]);
            *reinterpret_cast<uint4*>(&L[rowbase + sub + j * 8]) =
                make_uint4(lw[0], lw[1], lw[2], lw[3]);
        }
    }
}

// ---------------------------------------------------------------------------
// Kernel 2: MFMA flash attention. QTILE=128 (8 waves), KV-split nsplit,
// global_load_lds pipelined, defer-max. LDS 80KB -> 2 blocks/CU, 4 waves/SIMD.
// ---------------------------------------------------------------------------
__global__ __launch_bounds__(512, 4) void attn_kernel(
    const ushort_t* __restrict__ Qhi, const ushort_t* __restrict__ Qlo,
    const ushort_t* __restrict__ KhiS, const ushort_t* __restrict__ Klo,
    const ushort_t* __restrict__ VtS, float* __restrict__ Yp,
    float* __restrict__ ML, int NT)
{
    __shared__ __align__(16) char smem[81920];
    ushort_t* Kh0 = (ushort_t*)smem;
    ushort_t* Kh1 = (ushort_t*)(smem + 16384);
    ushort_t* Vl  = (ushort_t*)(smem + 32768);
    ushort_t* Kl  = (ushort_t*)(smem + 49152);
    ushort_t* Pl  = (ushort_t*)(smem + 65536);   // 16KB: 2KB per wave
    float*    stage = (float*)smem;              // epilogue reuse [128][132]

    const int tid  = threadIdx.x;
    const int w    = tid >> 6;      // wave 0..7
    const int lane = tid & 63;
    const int lq   = lane & 15;
    const int g    = lane >> 4;
    const int n0   = blockIdx.x * 128;
    const int h    = blockIdx.y;    // KV split index
    const int b    = blockIdx.z;

    // Q fragments in registers (linear layout)
    bf16x8 qh[4], ql[4];
    {
        const ushort_t* qbh = Qhi + (size_t)(b * NS + n0 + w * 16 + lq) * CCH;
        const ushort_t* qbl = Qlo + (size_t)(b * NS + n0 + w * 16 + lq) * CCH;
#pragma unroll
        for (int cs = 0; cs < 4; ++cs) {
            qh[cs] = *reinterpret_cast<const bf16x8*>(qbh + cs * 32 + g * 8);
            ql[cs] = *reinterpret_cast<const bf16x8*>(qbl + cs * 32 + g * 8);
        }
    }

    f32x4 yacc[8];
#pragma unroll
    for (int cf = 0; cf < 8; ++cf) yacc[cf] = (f32x4){0.f, 0.f, 0.f, 0.f};
    float m_run = -1e30f, l_run = 0.f;

    const ushort_t* Khg = KhiS + (size_t)b * NS * CCH;
    const ushort_t* Klg = Klo + (size_t)b * NS * CCH;
    const ushort_t* Vtg = VtS + (size_t)b * CCH * NS;

    const int ktbase = h * NT;

    uint4 tL[2];
    auto load_kl = [&](int ktg) {
        const int m0 = ktg * 64;
#pragma unroll
        for (int it = 0; it < 2; ++it) {
            int fi = it * 512 + tid;
            int kr = fi >> 4;
            int cc = fi & 15;
            tL[it] = *reinterpret_cast<const uint4*>(Klg + (size_t)(m0 + kr) * CCH + cc * 8);
        }
    };
    auto write_kl = [&]() {
#pragma unroll
        for (int it = 0; it < 2; ++it) {
            int fi = it * 512 + tid;
            int kr = fi >> 4;
            int cc = fi & 15;
            int swz = (cc & 8) | ((cc & 7) ^ (kr & 7));
            *reinterpret_cast<uint4*>(&Kl[kr * 128 + swz * 8]) = tL[it];
        }
    };
    auto gload_kh = [&](int ktg, ushort_t* dst) {
        const ushort_t* base = Khg + (size_t)(ktg * 64) * CCH;  // contiguous 16KB
#pragma unroll
        for (int i = 0; i < 2; ++i) {
            int off = i * 4096 + tid * 8;   // ushorts
            gload16(base + off, dst + off);
        }
    };
    auto gload_v = [&](int ktg) {
        const int m0 = ktg * 64;            // key column offset (ushorts)
#pragma unroll
        for (int i = 0; i < 2; ++i) {
            int o  = i * 4096 + tid * 8;    // ushort offset in 8K-ushort tile
            int cr = o >> 6;                // channel row 0..127
            int cw = o & 63;                // within-row ushort 0..63
            gload16(Vtg + (size_t)cr * NS + m0 + cw, Vl + o);
        }
    };

    // prologue: tile 0
    gload_kh(ktbase, Kh0);
    load_kl(ktbase);
    write_kl();
    __syncthreads();   // drains vmcnt: Kh0 + Kl ready

    for (int kt = 0; kt < NT; ++kt) {
        ushort_t* KhCur = (kt & 1) ? Kh1 : Kh0;
        ushort_t* KhNxt = (kt & 1) ? Kh0 : Kh1;
        const bool more = (kt + 1 < NT);

        gload_v(ktbase + kt);                     // V(t), needed after B1
        if (more) {
            gload_kh(ktbase + kt + 1, KhNxt);     // K-hi(t+1)
            load_kl(ktbase + kt + 1);             // K-lo(t+1) -> regs
        }

        // ---- QK^T: T[k=16kk+4g+r][q=lq] via 3-pass split
        f32x4 tacc[4];
#pragma unroll
        for (int kk = 0; kk < 4; ++kk) tacc[kk] = (f32x4){0.f, 0.f, 0.f, 0.f};
        __builtin_amdgcn_s_setprio(1);
#pragma unroll
        for (int cs = 0; cs < 4; ++cs) {
#pragma unroll
            for (int kk = 0; kk < 4; ++kk) {
                int kr = kk * 16 + lq;
                int cc = g + 4 * cs;
                int swz = (cc & 8) | ((cc & 7) ^ (kr & 7));
                bf16x8 ah = *reinterpret_cast<const bf16x8*>(&KhCur[kr * 128 + swz * 8]);
                bf16x8 al = *reinterpret_cast<const bf16x8*>(&Kl[kr * 128 + swz * 8]);
                tacc[kk] = __builtin_amdgcn_mfma_f32_16x16x32_bf16(ah, qh[cs], tacc[kk], 0, 0, 0);
                tacc[kk] = __builtin_amdgcn_mfma_f32_16x16x32_bf16(al, qh[cs], tacc[kk], 0, 0, 0);
                tacc[kk] = __builtin_amdgcn_mfma_f32_16x16x32_bf16(ah, ql[cs], tacc[kk], 0, 0, 0);
            }
        }
        __builtin_amdgcn_s_setprio(0);

        // ---- online softmax with defer-max (lane holds 16 keys of row q=lq)
        float mx = -1e30f;
#pragma unroll
        for (int kk = 0; kk < 4; ++kk)
#pragma unroll
            for (int r = 0; r < 4; ++r) mx = fmaxf(mx, tacc[kk][r]);
        mx = fmaxf(mx, __shfl_xor(mx, 16));
        mx = fmaxf(mx, __shfl_xor(mx, 32));

        const bool defer = __all(mx - m_run <= 8.0f);
        float mref, alpha;
        if (defer) {
            mref = m_run;
            alpha = 1.0f;
        } else {
            mref  = fmaxf(m_run, mx);
            alpha = __expf(m_run - mref);
        }

        float pr[4][4];
        float psum = 0.f;
#pragma unroll
        for (int kk = 0; kk < 4; ++kk)
#pragma unroll
            for (int r = 0; r < 4; ++r) {
                float v = __expf(tacc[kk][r] - mref);
                pr[kk][r] = v;
                psum += v;
            }
        psum += __shfl_xor(psum, 16);
        psum += __shfl_xor(psum, 32);

        // ---- pack P to bf16, wave-local swizzled LDS round trip
#pragma unroll
        for (int kk = 0; kk < 4; ++kk) {
            uint_t lo = (uint_t)f2bf(pr[kk][0]) | ((uint_t)f2bf(pr[kk][1]) << 16);
            uint_t hi = (uint_t)f2bf(pr[kk][2]) | ((uint_t)f2bf(pr[kk][3]) << 16);
            int kbase = kk * 16 + 4 * g;
            int swz = (kbase >> 3) ^ (lq & 7);
            uint2 val = make_uint2(lo, hi);
            *reinterpret_cast<uint2*>(&Pl[w * 1024 + lq * 64 + swz * 8 + (kbase & 7)]) = val;
        }
        bf16x8 pa[2];
#pragma unroll
        for (int s = 0; s < 2; ++s) {
            int swz = (g + 4 * s) ^ (lq & 7);
            pa[s] = *reinterpret_cast<const bf16x8*>(&Pl[w * 1024 + lq * 64 + swz * 8]);
        }

        __syncthreads();   // B1: V(t)/Kh(t+1) landed; all Kl(t) reads done
        if (more) write_kl();   // Kl(t+1) from regs

        // ---- rescale Y by alpha(q=4g+r) unless deferred, then Y += P V
        if (defer) {
            l_run += psum;
        } else {
            l_run = l_run * alpha + psum;
            m_run = mref;
            float a0 = __shfl(alpha, 4 * g + 0);
            float a1 = __shfl(alpha, 4 * g + 1);
            float a2 = __shfl(alpha, 4 * g + 2);
            float a3 = __shfl(alpha, 4 * g + 3);
#pragma unroll
            for (int cf = 0; cf < 8; ++cf) {
                yacc[cf][0] *= a0;
                yacc[cf][1] *= a1;
                yacc[cf][2] *= a2;
                yacc[cf][3] *= a3;
            }
        }
        __builtin_amdgcn_s_setprio(1);
#pragma unroll
        for (int cf = 0; cf < 8; ++cf) {
            int c = cf * 16 + lq;
#pragma unroll
            for (int s = 0; s < 2; ++s) {
                int swz = (g + 4 * s) ^ (c & 7);
                bf16x8 vb = *reinterpret_cast<const bf16x8*>(&Vl[c * 64 + swz * 8]);
                yacc[cf] = __builtin_amdgcn_mfma_f32_16x16x32_bf16(pa[s], vb, yacc[cf], 0, 0, 0);
            }
        }
        __builtin_amdgcn_s_setprio(0);

        __syncthreads();   // B2: PV reads of Vl done; Kl(t+1) visible
    }

    // ---- epilogue: coalesced unnormalized-Y store via LDS stage
#pragma unroll
    for (int cf = 0; cf < 8; ++cf)
#pragma unroll
        for (int r = 0; r < 4; ++r)
            stage[(w * 16 + 4 * g + r) * 132 + cf * 16 + lq] = yacc[cf][r];
    __syncthreads();
    float* Ybase = Yp + ((size_t)(h * BB + b) * NS + n0) * CCH;
#pragma unroll
    for (int u = 0; u < 8; ++u) {
        int idx = u * 512 + tid;
        int row = idx >> 5;
        int c4  = idx & 31;
        float4 v = ld4(&stage[row * 132 + c4 * 4]);
        st4(&Ybase[(size_t)row * CCH + c4 * 4], v);
    }
    if (g == 0) {
        size_t mi = ((size_t)(h * BB + b) * NS + n0 + w * 16 + lq) * 2;
        ML[mi + 0] = m_run;
        ML[mi + 1] = l_run;
    }
}

// ---------------------------------------------------------------------------
// Kernel 2b: merge KV-split partials -> normalized Ym [B][N][C] fp32.
// ---------------------------------------------------------------------------
__global__ __launch_bounds__(256) void merge_kernel(
    const float* __restrict__ Yp, const float* __restrict__ ML,
    float* __restrict__ Ym, int nsplit)
{
    const int total4 = BB * NS * CCH / 4;     // 2^19
    for (int i4 = blockIdx.x * 256 + threadIdx.x; i4 < total4;
         i4 += gridDim.x * 256) {
        int b = i4 >> 17;                     // NS*CCH/4 = 2^17
        int r = i4 & ((1 << 17) - 1);
        int n = r >> 5;                       // CCH/4 = 32

        float ms[4], ls[4];
        float m = -1e30f;
#pragma unroll
        for (int s = 0; s < 4; ++s) {
            if (s < nsplit) {
                size_t mi = ((size_t)(s * BB + b) * NS + n) * 2;
                ms[s] = ML[mi + 0];
                ls[s] = ML[mi + 1];
                m = fmaxf(m, ms[s]);
            }
        }
        float den = 0.f;
        float wt[4];
#pragma unroll
        for (int s = 0; s < 4; ++s) {
            if (s < nsplit) {
                wt[s] = __expf(ms[s] - m);
                den += ls[s] * wt[s];
            }
        }
        float inv = 1.0f / den;

        float4 acc = make_float4(0.f, 0.f, 0.f, 0.f);
#pragma unroll
        for (int s = 0; s < 4; ++s) {
            if (s < nsplit) {
                float a = wt[s] * inv;
                float4 y = ld4(&Yp[(size_t)(s * BB + b) * NS * CCH + (size_t)r * 4]);
                acc.x += a * y.x;
                acc.y += a * y.y;
                acc.z += a * y.z;
                acc.w += a * y.w;
            }
        }
        st4(&Ym[(size_t)b * NS * CCH + (size_t)r * 4], acc);
    }
}

// ---------------------------------------------------------------------------
// Kernel 3: z = Wz . Ym + bz (fp32), plus deterministic LN partial sums.
// ---------------------------------------------------------------------------
__global__ __launch_bounds__(256) void zgemm_kernel(
    const float* __restrict__ Ym, const float* __restrict__ Wz,
    const float* __restrict__ bz, float* __restrict__ Z,
    float* __restrict__ partials)
{
    __shared__ float Ws2[64 * 128];
    __shared__ float Ys2[64 * 128];
    __shared__ float red[8];

    const int tid = threadIdx.x;
    const int b   = blockIdx.z;
    const int ot  = blockIdx.y;
    const int n0  = blockIdx.x * 64;
    const int o0  = ot * 64;

#pragma unroll
    for (int u = 0; u < 8; ++u) {
        int fi = tid + 256 * u;
        int row = fi >> 5;
        int kc  = fi & 31;
        st4(&Ws2[row * 128 + (kc ^ (row & 7)) * 4],
            ld4(&Wz[(size_t)(o0 + row) * CCH + kc * 4]));
        st4(&Ys2[row * 128 + (kc ^ (row & 7)) * 4],
            ld4(&Ym[((size_t)b * NS + n0 + row) * CCH + kc * 4]));
    }
    __syncthreads();

    const int q  = tid & 15;
    const int tj = tid >> 4;

    float4 acc[4];
#pragma unroll
    for (int a = 0; a < 4; ++a) acc[a] = make_float4(0.f, 0.f, 0.f, 0.f);
#pragma unroll 4
    for (int g = 0; g < 32; ++g) {
        float4 yv[4], wv[4];
#pragma unroll
        for (int a = 0; a < 4; ++a) {
            int r = q + 16 * a;
            yv[a] = ld4(&Ys2[r * 128 + (g ^ (r & 7)) * 4]);
        }
#pragma unroll
        for (int jj = 0; jj < 4; ++jj) {
            int cj = 4 * tj + jj;
            wv[jj] = ld4(&Ws2[cj * 128 + (g ^ (cj & 7)) * 4]);
        }
#pragma unroll
        for (int a = 0; a < 4; ++a) {
            acc[a].x += dot4(yv[a], wv[0]);
            acc[a].y += dot4(yv[a], wv[1]);
            acc[a].z += dot4(yv[a], wv[2]);
            acc[a].w += dot4(yv[a], wv[3]);
        }
    }

    float4 bz4 = ld4(&bz[o0 + 4 * tj]);
    float s = 0.f, s2 = 0.f;
#pragma unroll
    for (int a = 0; a < 4; ++a) {
        int n = n0 + q + 16 * a;
        float v0 = acc[a].x + bz4.x;
        float v1 = acc[a].y + bz4.y;
        float v2 = acc[a].z + bz4.z;
        float v3 = acc[a].w + bz4.w;
        Z[(size_t)(b * CINC + o0 + 4 * tj + 0) * NS + n] = v0;
        Z[(size_t)(b * CINC + o0 + 4 * tj + 1) * NS + n] = v1;
        Z[(size_t)(b * CINC + o0 + 4 * tj + 2) * NS + n] = v2;
        Z[(size_t)(b * CINC + o0 + 4 * tj + 3) * NS + n] = v3;
        s  += v0 + v1 + v2 + v3;
        s2 += v0 * v0 + v1 * v1 + v2 * v2 + v3 * v3;
    }
#pragma unroll
    for (int off = 1; off < 64; off <<= 1) {
        s  += __shfl_xor(s, off);
        s2 += __shfl_xor(s2, off);
    }
    if ((tid & 63) == 0) { red[(tid >> 6) * 2] = s; red[(tid >> 6) * 2 + 1] = s2; }
    __syncthreads();
    if (tid == 0) {
        float ts  = red[0] + red[2] + red[4] + red[6];
        float ts2 = red[1] + red[3] + red[5] + red[7];
        int pidx = b * 256 + ot * 64 + blockIdx.x;
        partials[pidx * 2 + 0] = ts;
        partials[pidx * 2 + 1] = ts2;
    }
}

// ---------------------------------------------------------------------------
// Kernel 4: reduce partials -> per-batch (mean, rstd).
// ---------------------------------------------------------------------------
__global__ void ln_stats_kernel(const float* __restrict__ partials,
                                float* __restrict__ stats)
{
    const int b = blockIdx.x;
    const int t = threadIdx.x;  // 64
    float s = 0.f, s2 = 0.f;
#pragma unroll
    for (int u = 0; u < 4; ++u) {
        const float* pp = &partials[(size_t)(b * 256 + t + 64 * u) * 2];
        s  += pp[0];
        s2 += pp[1];
    }
#pragma unroll
    for (int off = 1; off < 64; off <<= 1) {
        s  += __shfl_xor(s, off);
        s2 += __shfl_xor(s2, off);
    }
    if (t == 0) {
        const float M = 1048576.f;
        float mean = s / M;
        float var  = s2 / M - mean * mean;
        stats[b * 2 + 0] = mean;
        stats[b * 2 + 1] = rsqrtf(var + LN_EPS);
    }
}

// ---------------------------------------------------------------------------
// Kernel 5: out = (z - mean)*rstd*gamma + beta + x
// ---------------------------------------------------------------------------
__global__ __launch_bounds__(256) void final_kernel(
    const float* __restrict__ Z, const float* __restrict__ x,
    const float* __restrict__ gamma, const float* __restrict__ beta,
    const float* __restrict__ stats, float* __restrict__ out)
{
    const int total4 = BB * CINC * NS / 4;
    for (int i4 = blockIdx.x * 256 + threadIdx.x; i4 < total4;
         i4 += gridDim.x * 256) {
        int b  = i4 >> 18;
        int r4 = i4 & ((1 << 18) - 1);
        float mean = stats[b * 2 + 0];
        float rstd = stats[b * 2 + 1];
        float4 zv = ld4(&Z[(size_t)i4 * 4]);
        float4 xv = ld4(&x[(size_t)i4 * 4]);
        float4 gv = ld4(&gamma[(size_t)r4 * 4]);
        float4 bv = ld4(&beta[(size_t)r4 * 4]);
        float4 o;
        o.x = (zv.x - mean) * rstd * gv.x + bv.x + xv.x;
        o.y = (zv.y - mean) * rstd * gv.y + bv.y + xv.y;
        o.z = (zv.z - mean) * rstd * gv.z + bv.z + xv.z;
        o.w = (zv.w - mean) * rstd * gv.w + bv.w + xv.w;
        st4(&out[(size_t)i4 * 4], o);
    }
}

extern "C" void kernel_launch(void* const* d_in, const int* in_sizes, int n_in,
                              void* d_out, int out_size, void* d_ws, size_t ws_size,
                              hipStream_t stream)
{
    const float* x     = (const float*)d_in[0];
    const float* Wg    = (const float*)d_in[1];
    const float* bg    = (const float*)d_in[2];
    const float* Wt    = (const float*)d_in[3];
    const float* bt    = (const float*)d_in[4];
    const float* Wp    = (const float*)d_in[5];
    const float* bp    = (const float*)d_in[6];
    const float* Wz    = (const float*)d_in[7];
    const float* bz    = (const float*)d_in[8];
    const float* gamma = (const float*)d_in[9];
    const float* beta  = (const float*)d_in[10];
    float* out = (float*)d_out;

    // bf16 bufs 20MB; Yp fp32 [nsplit][B][N][C]; ML; partials/stats.
    // Ym (8MB) aliases Qhi+Qlo (dead after attn); Z (16MB) aliases Yp
    // (dead after merge).
    const size_t SZH = (size_t)BB * NS * CCH * sizeof(ushort_t);  // 4 MB
    const size_t need4 = 5 * SZH
                       + (size_t)4 * BB * NS * CCH * sizeof(float)   // Yp x4
                       + (size_t)4 * BB * NS * 2 * sizeof(float)     // ML x4
                       + (size_t)BB * 256 * 2 * sizeof(float) + 256;
    const int nsplit = (ws_size >= need4) ? 4 : 2;
    const int NT = (NS / 64) / nsplit;   // 64-key tiles per split

    char* p = (char*)d_ws;
    ushort_t* Qhi  = (ushort_t*)p; p += SZH;
    ushort_t* Qlo  = (ushort_t*)p; p += SZH;
    ushort_t* KhiS = (ushort_t*)p; p += SZH;
    ushort_t* Klo  = (ushort_t*)p; p += SZH;
    ushort_t* VtS  = (ushort_t*)p; p += SZH;
    float* Yp = (float*)p; p += (size_t)nsplit * BB * NS * CCH * sizeof(float);
    float* ML = (float*)p; p += (size_t)nsplit * BB * NS * 2 * sizeof(float);
    float* partials = (float*)p; p += BB * 256 * 2 * sizeof(float);
    float* stats    = (float*)p;
    float* Ym = (float*)Qhi;   // 8MB alias, live after attn
    float* Z  = (float*)Yp;    // 16MB alias, live after merge

    proj_kernel<<<dim3(64, 6, BB), 256, 0, stream>>>(x, Wt, bt, Wp, bp, Wg, bg,
                                                     Qhi, Qlo, KhiS, Klo, VtS);
    attn_kernel<<<dim3(NS / 128, nsplit, BB), 512, 0, stream>>>(
        Qhi, Qlo, KhiS, Klo, VtS, Yp, ML, NT);
    merge_kernel<<<dim3(2048), 256, 0, stream>>>(Yp, ML, Ym, nsplit);
    zgemm_kernel<<<dim3(64, 4, BB), 256, 0, stream>>>(Ym, Wz, bz, Z, partials);
    ln_stats_kernel<<<dim3(BB), 64, 0, stream>>>(partials, stats);
    final_kernel<<<dim3(2048), 256, 0, stream>>>(Z, x, gamma, beta, stats, out);
}